// Round 8
// baseline (6874.100 us; speedup 1.0000x reference)
//
#include <hip/hip_runtime.h>
#include <math.h>

// Problem constants
#define BB 2048
#define LL 100
#define FF 64
#define EE 256
#define DD 256
#define NOUT 3

#define COMP(v, i) ((i) == 0 ? (v).x : (i) == 1 ? (v).y : (i) == 2 ? (v).z : (v).w)

__device__ __forceinline__ float sigmoidf_(float x) {
    return 1.0f / (1.0f + expf(-x));
}
// tanh via identity 1 - 2/(1+e^{2x}); ~2e-7 abs fp32 error, saturates correctly.
__device__ __forceinline__ float tanhf_(float x) {
    return 1.0f - 2.0f / (1.0f + expf(2.0f * x));
}

// ---------------------------------------------------------------------------
// Weight re-layout: dst[chunk*4096 + c*4 + kk] = W[(4*chunk+kk), c]
// where W = [Wlo ; Whi] stacked over k (klo rows then khi rows), both 1024 wide.
// Lets a thread owning cols (2tid,2tid+1) read 8 weights/chunk as two b128
// loads at immediate offsets with a single pointer bump per chunk.
// ---------------------------------------------------------------------------
__global__ __launch_bounds__(256) void wtrans(
    const float* __restrict__ Wlo, int klo,
    const float* __restrict__ Whi,
    float* __restrict__ dst, int total)
{
    int idx = blockIdx.x * 256 + threadIdx.x;
    if (idx >= total) return;
    int chunk = idx >> 12, rem = idx & 4095;
    int c = rem >> 2, kk = rem & 3;
    int k = chunk * 4 + kk;
    dst[idx] = (k < klo) ? Wlo[(size_t)k * 1024 + c]
                         : Whi[(size_t)(k - klo) * 1024 + c];
}

// ---------------------------------------------------------------------------
// Persistent encoder: ONE dispatch for all 100 timesteps (row-local recurrence).
// grid 256 x 512 threads; block owns 8 batch rows; wave w <-> row w.
//  - attention: wave w computes row w (lane = feature col), shuffle softmax
//  - gates: thread owns col-pair (2tid,2tid+1) x 8 rows; weights from the
//    chunk-major Wre (2 b128 loads + 1 ptr bump per 4-k chunk); activations
//    are wave-uniform LDS broadcasts
//  - epilogue: wave-local (lane -> 4 units of row w), c in registers
// 2 __syncthreads per step.
// ---------------------------------------------------------------------------
__global__ __launch_bounds__(512) void enc_all(
    const float* __restrict__ x,
    const float* __restrict__ Wa, const float* __restrict__ ba,
    const float* __restrict__ Wre, const float* __restrict__ be,
    float* __restrict__ enc_out)
{
    __shared__ float h_s[8 * 256];      // 8 KB
    __shared__ float x_s[8 * 64];       // 2 KB
    __shared__ float ein_s[8 * 64];     // 2 KB
    __shared__ float gate_s[8 * 1024];  // 32 KB

    const int row0 = blockIdx.x * 8;
    const int tid  = threadIdx.x;
    const int lane = tid & 63;
    const int w    = tid >> 6;

    const float  bav = ba[lane];
    const float2 be2 = *(const float2*)&be[2 * tid];
    const float* xrow = x + (size_t)(row0 + w) * LL * FF;
    float c_reg[4] = {0.f, 0.f, 0.f, 0.f};

    for (int t = 0; t < LL; ++t) {
        // stage x_t row w (wave-local; same-wave LDS write->read is ordered)
        x_s[w * 64 + lane] = xrow[t * FF + lane];

        // ---- input attention: wave w -> row w, lane -> feature col ----
        {
            float a = bav;
            #pragma unroll
            for (int k4 = 0; k4 < 64; k4 += 4) {
                float4 xa = *(const float4*)&x_s[w * 64 + k4];
                a += xa.x * Wa[(k4 + 0) * 64 + lane]
                   + xa.y * Wa[(k4 + 1) * 64 + lane]
                   + xa.z * Wa[(k4 + 2) * 64 + lane]
                   + xa.w * Wa[(k4 + 3) * 64 + lane];
            }
            if (t > 0) {
                #pragma unroll 4
                for (int k4 = 0; k4 < 256; k4 += 4) {
                    float4 ha = *(const float4*)&h_s[w * 256 + k4];
                    a += ha.x * Wa[(size_t)(64 + k4) * 64 + lane]
                       + ha.y * Wa[(size_t)(65 + k4) * 64 + lane]
                       + ha.z * Wa[(size_t)(66 + k4) * 64 + lane]
                       + ha.w * Wa[(size_t)(67 + k4) * 64 + lane];
                }
            }
            float e = tanhf_(a);
            float m = e;
            #pragma unroll
            for (int msk = 32; msk >= 1; msk >>= 1) m = fmaxf(m, __shfl_xor(m, msk, 64));
            float ev = expf(e - m);
            float s = ev;
            #pragma unroll
            for (int msk = 32; msk >= 1; msk >>= 1) s += __shfl_xor(s, msk, 64);
            ein_s[w * 64 + lane] = (ev / s) * x_s[w * 64 + lane];
        }
        __syncthreads();   // ein ready; prev-step h_s writes visible to all

        // ---- gates: thread -> cols (2tid, 2tid+1), 8 rows ----
        float2 acc2[8];
        #pragma unroll
        for (int r = 0; r < 8; ++r) acc2[r] = be2;

        const float* wp = Wre + (size_t)tid * 8;
        #pragma unroll 4
        for (int ch = 0; ch < 16; ++ch) {           // k = 0..63 (ein @ Wi)
            float4 w0 = *(const float4*)&wp[0];
            float4 w1 = *(const float4*)&wp[4];
            wp += 4096;
            float4 ev4[8];
            #pragma unroll
            for (int r = 0; r < 8; ++r) ev4[r] = *(const float4*)&ein_s[r * 64 + ch * 4];
            #pragma unroll
            for (int kk = 0; kk < 4; ++kk) {
                float wv0 = COMP(w0, kk), wv1 = COMP(w1, kk);
                #pragma unroll
                for (int r = 0; r < 8; ++r) {
                    float e = COMP(ev4[r], kk);
                    acc2[r].x += e * wv0; acc2[r].y += e * wv1;
                }
            }
        }
        if (t > 0) {
            #pragma unroll 4
            for (int ch = 0; ch < 64; ++ch) {       // k = 64..319 (h @ Wh)
                float4 w0 = *(const float4*)&wp[0];
                float4 w1 = *(const float4*)&wp[4];
                wp += 4096;
                float4 hv[8];
                #pragma unroll
                for (int r = 0; r < 8; ++r) hv[r] = *(const float4*)&h_s[r * 256 + ch * 4];
                #pragma unroll
                for (int kk = 0; kk < 4; ++kk) {
                    float wv0 = COMP(w0, kk), wv1 = COMP(w1, kk);
                    #pragma unroll
                    for (int r = 0; r < 8; ++r) {
                        float e = COMP(hv[r], kk);
                        acc2[r].x += e * wv0; acc2[r].y += e * wv1;
                    }
                }
            }
        }
        #pragma unroll
        for (int r = 0; r < 8; ++r) *(float2*)&gate_s[r * 1024 + 2 * tid] = acc2[r];
        __syncthreads();   // gates staged; all ein/h reads complete

        // ---- epilogue: wave-local. lane -> units lane*4..+3 of row w ----
        {
            float4 gi4 = *(const float4*)&gate_s[w * 1024 +       lane * 4];
            float4 gf4 = *(const float4*)&gate_s[w * 1024 + 256 + lane * 4];
            float4 gg4 = *(const float4*)&gate_s[w * 1024 + 512 + lane * 4];
            float4 go4 = *(const float4*)&gate_s[w * 1024 + 768 + lane * 4];
            float4 hn;
            c_reg[0] = sigmoidf_(gf4.x) * c_reg[0] + sigmoidf_(gi4.x) * tanhf_(gg4.x);
            hn.x = sigmoidf_(go4.x) * tanhf_(c_reg[0]);
            c_reg[1] = sigmoidf_(gf4.y) * c_reg[1] + sigmoidf_(gi4.y) * tanhf_(gg4.y);
            hn.y = sigmoidf_(go4.y) * tanhf_(c_reg[1]);
            c_reg[2] = sigmoidf_(gf4.z) * c_reg[2] + sigmoidf_(gi4.z) * tanhf_(gg4.z);
            hn.z = sigmoidf_(go4.z) * tanhf_(c_reg[2]);
            c_reg[3] = sigmoidf_(gf4.w) * c_reg[3] + sigmoidf_(gi4.w) * tanhf_(gg4.w);
            hn.w = sigmoidf_(go4.w) * tanhf_(c_reg[3]);
            *(float4*)&h_s[w * 256 + lane * 4] = hn;
            *(float4*)&enc_out[((size_t)t * BB + row0 + w) * 256 + lane * 4] = hn;
        }
        // no 3rd barrier: next-step attention reads only wave-local h_s/x_s;
        // cross-wave h_s/ein_s reads are guarded by the next sync1.
    }
}

// ---------------------------------------------------------------------------
// Fused decoder attention scores, Lin=2 timesteps per accumulator set
// (32 KB LDS -> 2x co-residency vs Lin=4). grid (B/16, 5), 256 threads.
// ---------------------------------------------------------------------------
#define SC_LIN 2
__global__ __launch_bounds__(256) void scores_fused(
    const float* __restrict__ enc_out, const float* __restrict__ Wd,
    const float* __restrict__ bd,
    const float* __restrict__ Wl, const float* __restrict__ bl,
    const float* __restrict__ hd, float* __restrict__ scores, int first)
{
    __shared__ float enc_s[SC_LIN * 16 * 256];   // 32 KB
    const int b0   = blockIdx.x * 16;
    const int l0   = blockIdx.y * 20;
    const int tid  = threadIdx.x;
    const int lane = tid & 63;
    const int rg   = tid >> 6;
    const int n0   = lane * 4;

    float hdp[4][4];
    {
        float4 bd4 = *(const float4*)&bd[n0];
        #pragma unroll
        for (int r = 0; r < 4; ++r) {
            hdp[r][0] = bd4.x; hdp[r][1] = bd4.y; hdp[r][2] = bd4.z; hdp[r][3] = bd4.w;
        }
    }
    if (!first) {
        for (int v = tid; v < 1024; v += 256) {
            int r = v >> 6, qq = v & 63;
            *(float4*)&enc_s[r * 256 + qq * 4] =
                *(const float4*)(hd + (size_t)(b0 + r) * 256 + qq * 4);
        }
        __syncthreads();
        const float* wb = Wd + 256 * 256;
        #pragma unroll 2
        for (int k = 0; k < 256; k += 4) {
            float4 hv[4];
            #pragma unroll
            for (int r = 0; r < 4; ++r) hv[r] = *(const float4*)&enc_s[(rg * 4 + r) * 256 + k];
            #pragma unroll
            for (int kk = 0; kk < 4; ++kk) {
                float4 wv = *(const float4*)&wb[(size_t)(k + kk) * 256 + n0];
                #pragma unroll
                for (int r = 0; r < 4; ++r) {
                    float e = COMP(hv[r], kk);
                    hdp[r][0] += e * wv.x; hdp[r][1] += e * wv.y;
                    hdp[r][2] += e * wv.z; hdp[r][3] += e * wv.w;
                }
            }
        }
        __syncthreads();
    }
    float4 wl4 = *(const float4*)&Wl[n0];
    const float blv = bl[0];

    for (int lo = 0; lo < 20; lo += SC_LIN) {
        for (int v = tid; v < SC_LIN * 16 * 64; v += 256) {
            int li = v >> 10, rem = v & 1023;
            int r = rem >> 6, qq = rem & 63;
            *(float4*)&enc_s[li * 4096 + r * 256 + qq * 4] =
                *(const float4*)(enc_out + (size_t)(l0 + lo + li) * (BB * 256)
                                 + (size_t)(b0 + r) * 256 + qq * 4);
        }
        __syncthreads();

        float acc[SC_LIN][4][4];
        #pragma unroll
        for (int li = 0; li < SC_LIN; ++li)
            #pragma unroll
            for (int r = 0; r < 4; ++r)
                #pragma unroll
                for (int c = 0; c < 4; ++c) acc[li][r][c] = hdp[r][c];

        for (int k = 0; k < 256; k += 4) {
            float4 wv[4];
            #pragma unroll
            for (int kk = 0; kk < 4; ++kk)
                wv[kk] = *(const float4*)&Wd[(size_t)(k + kk) * 256 + n0];
            #pragma unroll
            for (int li = 0; li < SC_LIN; ++li) {
                float4 ev[4];
                #pragma unroll
                for (int r = 0; r < 4; ++r)
                    ev[r] = *(const float4*)&enc_s[li * 4096 + (rg * 4 + r) * 256 + k];
                #pragma unroll
                for (int kk = 0; kk < 4; ++kk) {
                    #pragma unroll
                    for (int r = 0; r < 4; ++r) {
                        float e = COMP(ev[r], kk);
                        acc[li][r][0] += e * wv[kk].x; acc[li][r][1] += e * wv[kk].y;
                        acc[li][r][2] += e * wv[kk].z; acc[li][r][3] += e * wv[kk].w;
                    }
                }
            }
        }
        #pragma unroll
        for (int li = 0; li < SC_LIN; ++li) {
            #pragma unroll
            for (int r = 0; r < 4; ++r) {
                float p = tanhf_(acc[li][r][0]) * wl4.x + tanhf_(acc[li][r][1]) * wl4.y
                        + tanhf_(acc[li][r][2]) * wl4.z + tanhf_(acc[li][r][3]) * wl4.w;
                #pragma unroll
                for (int msk = 32; msk >= 1; msk >>= 1) p += __shfl_xor(p, msk, 64);
                if (lane == 0)
                    scores[(size_t)(l0 + lo + li) * BB + b0 + rg * 4 + r] = p + blv;
            }
        }
        __syncthreads();
    }
}

// ---------------------------------------------------------------------------
// softmax over L + ctx from scores buffer. Block = 8 rows.
// ---------------------------------------------------------------------------
__global__ __launch_bounds__(256) void softmax_ctx(
    const float* __restrict__ scores, const float* __restrict__ enc_out,
    float* __restrict__ ctx)
{
    __shared__ float al_s[8 * 100];
    const int b0  = blockIdx.x * 8;
    const int tid = threadIdx.x;
    for (int v = tid; v < 800; v += 256) {
        int r = v / 100, l = v - r * 100;
        al_s[r * 100 + l] = scores[(size_t)l * BB + b0 + r];
    }
    __syncthreads();
    if (tid < 8) {
        float m = -1e30f;
        for (int l = 0; l < LL; ++l) m = fmaxf(m, al_s[tid * 100 + l]);
        float s = 0.f;
        for (int l = 0; l < LL; ++l) { float e = expf(al_s[tid * 100 + l] - m); al_s[tid * 100 + l] = e; s += e; }
        float inv = 1.f / s;
        for (int l = 0; l < LL; ++l) al_s[tid * 100 + l] *= inv;
    }
    __syncthreads();
    float acc[8] = {};
    for (int l = 0; l < LL; ++l) {
        const float* er = enc_out + (size_t)l * (BB * 256) + (size_t)b0 * 256 + tid;
        #pragma unroll
        for (int r = 0; r < 8; ++r) acc[r] += al_s[r * 100 + l] * er[r * 256];
    }
    for (int r = 0; r < 8; ++r) ctx[(size_t)(b0 + r) * 256 + tid] = acc[r];
}

// ---------------------------------------------------------------------------
// Decoder LSTM cell, enc_all-style: grid 256 x 512 threads, block = 8 rows,
// col-pair weights from chunk-major Wre (k<256: Wdi, k>=256: Wdh).
// hd updated in place (block reads/writes only its own rows; kernels are
// stream-ordered vs scores_fused).
// ---------------------------------------------------------------------------
__global__ __launch_bounds__(512) void dec_step(
    const float* __restrict__ ctxp, const float* __restrict__ Wre,
    const float* __restrict__ bdec,
    float* __restrict__ hd, float* __restrict__ c_st, int first)
{
    __shared__ float ct_s[8 * 256];
    __shared__ float hd_s[8 * 256];
    __shared__ float gate_s[8 * 1024];
    const int row0 = blockIdx.x * 8;
    const int tid  = threadIdx.x;
    const int lane = tid & 63, w = tid >> 6;

    ((float4*)ct_s)[tid] = ((const float4*)(ctxp + (size_t)row0 * 256))[tid];
    if (!first)
        ((float4*)hd_s)[tid] = ((const float4*)(hd + (size_t)row0 * 256))[tid];
    __syncthreads();

    float2 acc2[8];
    {
        const float2 be2 = *(const float2*)&bdec[2 * tid];
        #pragma unroll
        for (int r = 0; r < 8; ++r) acc2[r] = be2;
    }
    const float* wp = Wre + (size_t)tid * 8;
    #pragma unroll 4
    for (int ch = 0; ch < 64; ++ch) {             // k = 0..255 (ctx @ Wdi)
        float4 w0 = *(const float4*)&wp[0];
        float4 w1 = *(const float4*)&wp[4];
        wp += 4096;
        float4 cv[8];
        #pragma unroll
        for (int r = 0; r < 8; ++r) cv[r] = *(const float4*)&ct_s[r * 256 + ch * 4];
        #pragma unroll
        for (int kk = 0; kk < 4; ++kk) {
            float wv0 = COMP(w0, kk), wv1 = COMP(w1, kk);
            #pragma unroll
            for (int r = 0; r < 8; ++r) {
                float e = COMP(cv[r], kk);
                acc2[r].x += e * wv0; acc2[r].y += e * wv1;
            }
        }
    }
    if (!first) {
        #pragma unroll 4
        for (int ch = 0; ch < 64; ++ch) {         // k = 256..511 (hd @ Wdh)
            float4 w0 = *(const float4*)&wp[0];
            float4 w1 = *(const float4*)&wp[4];
            wp += 4096;
            float4 hv[8];
            #pragma unroll
            for (int r = 0; r < 8; ++r) hv[r] = *(const float4*)&hd_s[r * 256 + ch * 4];
            #pragma unroll
            for (int kk = 0; kk < 4; ++kk) {
                float wv0 = COMP(w0, kk), wv1 = COMP(w1, kk);
                #pragma unroll
                for (int r = 0; r < 8; ++r) {
                    float e = COMP(hv[r], kk);
                    acc2[r].x += e * wv0; acc2[r].y += e * wv1;
                }
            }
        }
    }
    #pragma unroll
    for (int r = 0; r < 8; ++r) *(float2*)&gate_s[r * 1024 + 2 * tid] = acc2[r];
    __syncthreads();

    // epilogue: wave-local row w, lane -> 4 units
    {
        float4 gi4 = *(const float4*)&gate_s[w * 1024 +       lane * 4];
        float4 gf4 = *(const float4*)&gate_s[w * 1024 + 256 + lane * 4];
        float4 gg4 = *(const float4*)&gate_s[w * 1024 + 512 + lane * 4];
        float4 go4 = *(const float4*)&gate_s[w * 1024 + 768 + lane * 4];
        size_t ci = (size_t)(row0 + w) * 256 + lane * 4;
        float4 c4 = first ? make_float4(0.f, 0.f, 0.f, 0.f)
                          : *(const float4*)&c_st[ci];
        float4 cn, hn;
        cn.x = sigmoidf_(gf4.x) * c4.x + sigmoidf_(gi4.x) * tanhf_(gg4.x);
        hn.x = sigmoidf_(go4.x) * tanhf_(cn.x);
        cn.y = sigmoidf_(gf4.y) * c4.y + sigmoidf_(gi4.y) * tanhf_(gg4.y);
        hn.y = sigmoidf_(go4.y) * tanhf_(cn.y);
        cn.z = sigmoidf_(gf4.z) * c4.z + sigmoidf_(gi4.z) * tanhf_(gg4.z);
        hn.z = sigmoidf_(go4.z) * tanhf_(cn.z);
        cn.w = sigmoidf_(gf4.w) * c4.w + sigmoidf_(gi4.w) * tanhf_(gg4.w);
        hn.w = sigmoidf_(go4.w) * tanhf_(cn.w);
        *(float4*)&c_st[ci] = cn;
        *(float4*)&hd[ci]   = hn;
    }
}

// ---------------------------------------------------------------------------
// Head: fc = tanh(h_d@Wf+bf); out[:,step] = tanh(fc@Wo+bo). Block = 16 rows.
// ---------------------------------------------------------------------------
__global__ __launch_bounds__(256) void head_k(
    const float* __restrict__ hd, const float* __restrict__ Wf,
    const float* __restrict__ bf, const float* __restrict__ Wo,
    const float* __restrict__ bo, float* __restrict__ out, int step)
{
    __shared__ float hd_s[16 * 256];
    __shared__ float fc_s[16 * 128];
    const int b0  = blockIdx.x * 16;
    const int tid = threadIdx.x;
    {
        const float4* hg = (const float4*)(hd + (size_t)b0 * 256);
        for (int i = tid; i < 1024; i += 256) ((float4*)hd_s)[i] = hg[i];
    }
    __syncthreads();
    {
        const int f = tid & 127, rg = tid >> 7;
        float acc[8];
        float bfv = bf[f];
        #pragma unroll
        for (int rr = 0; rr < 8; ++rr) acc[rr] = bfv;
        const float* wp = Wf + f;
        #pragma unroll 2
        for (int k = 0; k < 256; ++k) {
            float wv = wp[k * 128];
            #pragma unroll
            for (int rr = 0; rr < 8; ++rr) acc[rr] += hd_s[(rg * 8 + rr) * 256 + k] * wv;
        }
        for (int rr = 0; rr < 8; ++rr) fc_s[(rg * 8 + rr) * 128 + f] = tanhf_(acc[rr]);
    }
    __syncthreads();
    {
        const int lane = tid & 63, w = tid >> 6;
        const float bov = bo[0];
        #pragma unroll
        for (int rr = 0; rr < 4; ++rr) {
            int r = w * 4 + rr;
            float p = fc_s[r * 128 + lane] * Wo[lane] + fc_s[r * 128 + 64 + lane] * Wo[64 + lane];
            #pragma unroll
            for (int msk = 32; msk >= 1; msk >>= 1) p += __shfl_xor(p, msk, 64);
            if (lane == 0) out[(size_t)(b0 + r) * NOUT + step] = tanhf_(p + bov);
        }
    }
}

extern "C" void kernel_launch(void* const* d_in, const int* in_sizes, int n_in,
                              void* d_out, int out_size, void* d_ws, size_t ws_size,
                              hipStream_t stream)
{
    const float* x    = (const float*)d_in[0];
    const float* Wa   = (const float*)d_in[1];
    const float* ba   = (const float*)d_in[2];
    const float* Wi   = (const float*)d_in[3];
    const float* Wh   = (const float*)d_in[4];
    const float* be   = (const float*)d_in[5];
    const float* Wd   = (const float*)d_in[6];
    const float* bd   = (const float*)d_in[7];
    const float* Wl   = (const float*)d_in[8];
    const float* bl   = (const float*)d_in[9];
    const float* Wdi  = (const float*)d_in[10];
    const float* Wdh  = (const float*)d_in[11];
    const float* bdec = (const float*)d_in[12];
    const float* Wf   = (const float*)d_in[13];
    const float* bf   = (const float*)d_in[14];
    const float* Wo   = (const float*)d_in[15];
    const float* bo   = (const float*)d_in[16];
    float* out = (float*)d_out;

    // ws layout (floats): enc_out | hd | c_d | ctx | scores | Wenc_re | Wdec_re
    // total 55,058,432 floats = 220.2 MB (< the 221 MB verified in round 2)
    const size_t f_enc    = (size_t)LL * BB * EE;     // 52,428,800
    const size_t f_state  = (size_t)BB * EE;          // 524,288
    const size_t f_scores = (size_t)LL * BB;          // 204,800
    const size_t f_wenc   = 320 * 1024;               // 327,680
    const size_t f_wdec   = 512 * 1024;               // 524,288
    const size_t need_f   = f_enc + 3 * f_state + f_scores + f_wenc + f_wdec;

    float* ws      = (float*)d_ws;
    float* enc_out = ws;
    float* hd      = enc_out + f_enc;
    float* c_d     = hd + f_state;
    float* ctx     = c_d + f_state;
    float* scores  = ctx + f_state;
    float* Wenc_re = scores + f_scores;
    float* Wdec_re = Wenc_re + f_wenc;

    if (ws_size < need_f * sizeof(float)) return;   // diagnostic clean-fail

    // one-time (per call) weight re-layouts
    wtrans<<<(int)((f_wenc + 255) / 256), 256, 0, stream>>>(Wi, 64, Wh, Wenc_re, (int)f_wenc);
    wtrans<<<(int)((f_wdec + 255) / 256), 256, 0, stream>>>(Wdi, 256, Wdh, Wdec_re, (int)f_wdec);

    // persistent encoder: one dispatch for all 100 timesteps
    enc_all<<<BB / 8, 512, 0, stream>>>(x, Wa, ba, Wenc_re, be, enc_out);

    for (int s = 0; s < NOUT; ++s) {
        scores_fused<<<dim3(BB / 16, 5), 256, 0, stream>>>(
            enc_out, Wd, bd, Wl, bl, hd, scores, s == 0);
        softmax_ctx<<<BB / 8, 256, 0, stream>>>(scores, enc_out, ctx);
        dec_step<<<BB / 8, 512, 0, stream>>>(ctx, Wdec_re, bdec, hd, c_d, s == 0);
        head_k<<<BB / 16, 256, 0, stream>>>(hd, Wf, bf, Wo, bo, out, s);
    }
}

// Round 9
// 5553.206 us; speedup vs baseline: 1.2379x; 1.2379x over previous
//
#include <hip/hip_runtime.h>
#include <math.h>

// Problem constants
#define BB 2048
#define LL 100
#define FF 64
#define EE 256
#define DD 256
#define NOUT 3

#define COMP(v, i) ((i) == 0 ? (v).x : (i) == 1 ? (v).y : (i) == 2 ? (v).z : (v).w)

__device__ __forceinline__ float sigmoidf_(float x) {
    return 1.0f / (1.0f + expf(-x));
}
// tanh via identity 1 - 2/(1+e^{2x}); ~2e-7 abs fp32 error, saturates correctly.
__device__ __forceinline__ float tanhf_(float x) {
    return 1.0f - 2.0f / (1.0f + expf(2.0f * x));
}

// ---------------------------------------------------------------------------
// Packet weight layout for enc gates: dst[ch*4096 + ct*16 + kk*4 + cc]
//   = W[k=ch*4+kk][c=ct*4+cc],  W = [Wi(64 rows); Wh(256 rows)], 1024 wide.
// Thread ct reads its 16 floats per 4-k chunk as 4 b128 at imm offsets.
// ---------------------------------------------------------------------------
__global__ __launch_bounds__(256) void wpack(
    const float* __restrict__ Wlo, int klo,
    const float* __restrict__ Whi,
    float* __restrict__ dst, int total)
{
    int idx = blockIdx.x * 256 + threadIdx.x;
    if (idx >= total) return;
    int ch = idx >> 12, ct = (idx >> 4) & 255, kk = (idx >> 2) & 3, cc = idx & 3;
    int k = ch * 4 + kk, c = ct * 4 + cc;
    dst[idx] = (k < klo) ? Wlo[(size_t)k * 1024 + c]
                         : Whi[(size_t)(k - klo) * 1024 + c];
}

// Old col-pair chunk-major layout (used by dec_step):
// dst[chunk*4096 + c*4 + kk] = W[(4*chunk+kk), c], W=[Wlo;Whi] stacked.
__global__ __launch_bounds__(256) void wtrans(
    const float* __restrict__ Wlo, int klo,
    const float* __restrict__ Whi,
    float* __restrict__ dst, int total)
{
    int idx = blockIdx.x * 256 + threadIdx.x;
    if (idx >= total) return;
    int chunk = idx >> 12, rem = idx & 4095;
    int c = rem >> 2, kk = rem & 3;
    int k = chunk * 4 + kk;
    dst[idx] = (k < klo) ? Wlo[(size_t)k * 1024 + c]
                         : Whi[(size_t)(k - klo) * 1024 + c];
}

// Wa transpose: WaT[c*320 + k] = Wa[k*64 + c]  (c<64, k<320)
__global__ __launch_bounds__(256) void watrans(
    const float* __restrict__ Wa, float* __restrict__ dst)
{
    int idx = blockIdx.x * 256 + threadIdx.x;
    if (idx >= 64 * 320) return;
    int c = idx / 320, k = idx - c * 320;
    dst[idx] = Wa[(size_t)k * 64 + c];
}

// ---------------------------------------------------------------------------
// Persistent encoder, k-split + 4-col packets.
// grid 256 x 512; block owns 8 rows; wave w <-> row w for attention/epilogue.
// Gates: thread = (half = tid>>8, ct = tid&255) -> cols ct*4..+3, k-range
// half*160..+159. One activation broadcast (b128) feeds 16 FMAs; weight
// packets are 4 b128 at immediate offsets, 1 ptr bump per chunk.
// Partial sums combined through gate_s[2] staging. 2 barriers/step.
// ---------------------------------------------------------------------------
__global__ __launch_bounds__(512) void enc_all(
    const float* __restrict__ x,
    const float* __restrict__ WaT, const float* __restrict__ ba,
    const float* __restrict__ Wre, const float* __restrict__ be,
    float* __restrict__ enc_out)
{
    __shared__ float act_s[8 * 320];       // 10 KB [row][0:64 ein | 64:320 h]
    __shared__ float x_s[8 * 64];          // 2 KB
    __shared__ float gate_s[2][8 * 1024];  // 64 KB partial-sum halves

    const int row0 = blockIdx.x * 8;
    const int tid  = threadIdx.x;
    const int lane = tid & 63;
    const int w    = tid >> 6;       // wave 0..7 == row
    const int half = tid >> 8;       // k-split half
    const int ct   = tid & 255;      // col-quad owner
    const int c0   = ct * 4;

    float4 bias4;
    {
        float4 b4 = *(const float4*)&be[c0];
        bias4 = half == 0 ? b4 : make_float4(0.f, 0.f, 0.f, 0.f);
    }
    const float  bav  = ba[lane];
    const float* waT  = WaT + (size_t)lane * 320;
    const float* xrow = x + (size_t)(row0 + w) * LL * FF;
    float c_reg[4] = {0.f, 0.f, 0.f, 0.f};

    for (int t = 0; t < LL; ++t) {
        // stage x_t row w (wave-local)
        x_s[w * 64 + lane] = xrow[t * FF + lane];

        // ---- input attention: wave w -> row w, lane -> feature col ----
        {
            float a = bav;
            #pragma unroll
            for (int k4 = 0; k4 < 64; k4 += 4) {
                float4 wv = *(const float4*)&waT[k4];
                float4 xa = *(const float4*)&x_s[w * 64 + k4];
                a += xa.x * wv.x + xa.y * wv.y + xa.z * wv.z + xa.w * wv.w;
            }
            if (t > 0) {
                #pragma unroll 4
                for (int k4 = 64; k4 < 320; k4 += 4) {
                    float4 wv = *(const float4*)&waT[k4];
                    float4 ha = *(const float4*)&act_s[w * 320 + k4];
                    a += ha.x * wv.x + ha.y * wv.y + ha.z * wv.z + ha.w * wv.w;
                }
            }
            float e = tanhf_(a);
            float m = e;
            #pragma unroll
            for (int msk = 32; msk >= 1; msk >>= 1) m = fmaxf(m, __shfl_xor(m, msk, 64));
            float ev = expf(e - m);
            float s = ev;
            #pragma unroll
            for (int msk = 32; msk >= 1; msk >>= 1) s += __shfl_xor(s, msk, 64);
            act_s[w * 320 + lane] = (ev / s) * x_s[w * 64 + lane];
        }
        __syncthreads();   // sync1: ein + prev-h visible to all waves

        // ---- gates: thread -> 4 cols, half k-range, 8 rows ----
        float4 acc[8];
        #pragma unroll
        for (int r = 0; r < 8; ++r) acc[r] = bias4;

        const float* wp = Wre + (size_t)half * 40 * 4096 + (size_t)ct * 16;
        const int kb  = half * 160;
        const int nch = (t == 0) ? (half == 0 ? 16 : 0) : 40;
        #pragma unroll 2
        for (int ch = 0; ch < nch; ++ch) {
            float4 w0 = *(const float4*)&wp[0];
            float4 w1 = *(const float4*)&wp[4];
            float4 w2 = *(const float4*)&wp[8];
            float4 w3 = *(const float4*)&wp[12];
            wp += 4096;
            const int ko = kb + ch * 4;
            #pragma unroll
            for (int r = 0; r < 8; ++r) {
                float4 av = *(const float4*)&act_s[r * 320 + ko];
                acc[r].x += av.x * w0.x; acc[r].y += av.x * w0.y;
                acc[r].z += av.x * w0.z; acc[r].w += av.x * w0.w;
                acc[r].x += av.y * w1.x; acc[r].y += av.y * w1.y;
                acc[r].z += av.y * w1.z; acc[r].w += av.y * w1.w;
                acc[r].x += av.z * w2.x; acc[r].y += av.z * w2.y;
                acc[r].z += av.z * w2.z; acc[r].w += av.z * w2.w;
                acc[r].x += av.w * w3.x; acc[r].y += av.w * w3.y;
                acc[r].z += av.w * w3.z; acc[r].w += av.w * w3.w;
            }
        }
        #pragma unroll
        for (int r = 0; r < 8; ++r)
            *(float4*)&gate_s[half][r * 1024 + c0] = acc[r];
        __syncthreads();   // sync2: both halves staged

        // ---- epilogue: wave-local. lane -> units lane*4..+3 of row w ----
        {
            const float* g0 = &gate_s[0][w * 1024 + lane * 4];
            const float* g1 = &gate_s[1][w * 1024 + lane * 4];
            float4 giA = *(const float4*)&g0[0],    giB = *(const float4*)&g1[0];
            float4 gfA = *(const float4*)&g0[256],  gfB = *(const float4*)&g1[256];
            float4 ggA = *(const float4*)&g0[512],  ggB = *(const float4*)&g1[512];
            float4 goA = *(const float4*)&g0[768],  goB = *(const float4*)&g1[768];
            float gi[4] = { giA.x + giB.x, giA.y + giB.y, giA.z + giB.z, giA.w + giB.w };
            float gf[4] = { gfA.x + gfB.x, gfA.y + gfB.y, gfA.z + gfB.z, gfA.w + gfB.w };
            float gg[4] = { ggA.x + ggB.x, ggA.y + ggB.y, ggA.z + ggB.z, ggA.w + ggB.w };
            float go[4] = { goA.x + goB.x, goA.y + goB.y, goA.z + goB.z, goA.w + goB.w };
            float4 hn;
            #pragma unroll
            for (int uu = 0; uu < 4; ++uu) {
                float cn = sigmoidf_(gf[uu]) * c_reg[uu] + sigmoidf_(gi[uu]) * tanhf_(gg[uu]);
                c_reg[uu] = cn;
                float hv = sigmoidf_(go[uu]) * tanhf_(cn);
                if (uu == 0) hn.x = hv; else if (uu == 1) hn.y = hv;
                else if (uu == 2) hn.z = hv; else hn.w = hv;
            }
            *(float4*)&act_s[w * 320 + 64 + lane * 4] = hn;
            *(float4*)&enc_out[((size_t)t * BB + row0 + w) * 256 + lane * 4] = hn;
        }
        // no 3rd barrier: next attention reads only wave-local act_s/x_s;
        // cross-wave reads are guarded by the next sync1.
    }
}

// ---------------------------------------------------------------------------
// Fused decoder attention scores, Lin=2. grid (B/16, 5), 256 threads.
// ---------------------------------------------------------------------------
#define SC_LIN 2
__global__ __launch_bounds__(256) void scores_fused(
    const float* __restrict__ enc_out, const float* __restrict__ Wd,
    const float* __restrict__ bd,
    const float* __restrict__ Wl, const float* __restrict__ bl,
    const float* __restrict__ hd, float* __restrict__ scores, int first)
{
    __shared__ float enc_s[SC_LIN * 16 * 256];   // 32 KB
    const int b0   = blockIdx.x * 16;
    const int l0   = blockIdx.y * 20;
    const int tid  = threadIdx.x;
    const int lane = tid & 63;
    const int rg   = tid >> 6;
    const int n0   = lane * 4;

    float hdp[4][4];
    {
        float4 bd4 = *(const float4*)&bd[n0];
        #pragma unroll
        for (int r = 0; r < 4; ++r) {
            hdp[r][0] = bd4.x; hdp[r][1] = bd4.y; hdp[r][2] = bd4.z; hdp[r][3] = bd4.w;
        }
    }
    if (!first) {
        for (int v = tid; v < 1024; v += 256) {
            int r = v >> 6, qq = v & 63;
            *(float4*)&enc_s[r * 256 + qq * 4] =
                *(const float4*)(hd + (size_t)(b0 + r) * 256 + qq * 4);
        }
        __syncthreads();
        const float* wb = Wd + 256 * 256;
        #pragma unroll 2
        for (int k = 0; k < 256; k += 4) {
            float4 hv[4];
            #pragma unroll
            for (int r = 0; r < 4; ++r) hv[r] = *(const float4*)&enc_s[(rg * 4 + r) * 256 + k];
            #pragma unroll
            for (int kk = 0; kk < 4; ++kk) {
                float4 wv = *(const float4*)&wb[(size_t)(k + kk) * 256 + n0];
                #pragma unroll
                for (int r = 0; r < 4; ++r) {
                    float e = COMP(hv[r], kk);
                    hdp[r][0] += e * wv.x; hdp[r][1] += e * wv.y;
                    hdp[r][2] += e * wv.z; hdp[r][3] += e * wv.w;
                }
            }
        }
        __syncthreads();
    }
    float4 wl4 = *(const float4*)&Wl[n0];
    const float blv = bl[0];

    for (int lo = 0; lo < 20; lo += SC_LIN) {
        for (int v = tid; v < SC_LIN * 16 * 64; v += 256) {
            int li = v >> 10, rem = v & 1023;
            int r = rem >> 6, qq = rem & 63;
            *(float4*)&enc_s[li * 4096 + r * 256 + qq * 4] =
                *(const float4*)(enc_out + (size_t)(l0 + lo + li) * (BB * 256)
                                 + (size_t)(b0 + r) * 256 + qq * 4);
        }
        __syncthreads();

        float acc[SC_LIN][4][4];
        #pragma unroll
        for (int li = 0; li < SC_LIN; ++li)
            #pragma unroll
            for (int r = 0; r < 4; ++r)
                #pragma unroll
                for (int c = 0; c < 4; ++c) acc[li][r][c] = hdp[r][c];

        for (int k = 0; k < 256; k += 4) {
            float4 wv[4];
            #pragma unroll
            for (int kk = 0; kk < 4; ++kk)
                wv[kk] = *(const float4*)&Wd[(size_t)(k + kk) * 256 + n0];
            #pragma unroll
            for (int li = 0; li < SC_LIN; ++li) {
                float4 ev[4];
                #pragma unroll
                for (int r = 0; r < 4; ++r)
                    ev[r] = *(const float4*)&enc_s[li * 4096 + (rg * 4 + r) * 256 + k];
                #pragma unroll
                for (int kk = 0; kk < 4; ++kk) {
                    #pragma unroll
                    for (int r = 0; r < 4; ++r) {
                        float e = COMP(ev[r], kk);
                        acc[li][r][0] += e * wv[kk].x; acc[li][r][1] += e * wv[kk].y;
                        acc[li][r][2] += e * wv[kk].z; acc[li][r][3] += e * wv[kk].w;
                    }
                }
            }
        }
        #pragma unroll
        for (int li = 0; li < SC_LIN; ++li) {
            #pragma unroll
            for (int r = 0; r < 4; ++r) {
                float p = tanhf_(acc[li][r][0]) * wl4.x + tanhf_(acc[li][r][1]) * wl4.y
                        + tanhf_(acc[li][r][2]) * wl4.z + tanhf_(acc[li][r][3]) * wl4.w;
                #pragma unroll
                for (int msk = 32; msk >= 1; msk >>= 1) p += __shfl_xor(p, msk, 64);
                if (lane == 0)
                    scores[(size_t)(l0 + lo + li) * BB + b0 + rg * 4 + r] = p + blv;
            }
        }
        __syncthreads();
    }
}

// ---------------------------------------------------------------------------
// softmax over L + ctx from scores buffer. Block = 8 rows.
// ---------------------------------------------------------------------------
__global__ __launch_bounds__(256) void softmax_ctx(
    const float* __restrict__ scores, const float* __restrict__ enc_out,
    float* __restrict__ ctx)
{
    __shared__ float al_s[8 * 100];
    const int b0  = blockIdx.x * 8;
    const int tid = threadIdx.x;
    for (int v = tid; v < 800; v += 256) {
        int r = v / 100, l = v - r * 100;
        al_s[r * 100 + l] = scores[(size_t)l * BB + b0 + r];
    }
    __syncthreads();
    if (tid < 8) {
        float m = -1e30f;
        for (int l = 0; l < LL; ++l) m = fmaxf(m, al_s[tid * 100 + l]);
        float s = 0.f;
        for (int l = 0; l < LL; ++l) { float e = expf(al_s[tid * 100 + l] - m); al_s[tid * 100 + l] = e; s += e; }
        float inv = 1.f / s;
        for (int l = 0; l < LL; ++l) al_s[tid * 100 + l] *= inv;
    }
    __syncthreads();
    float acc[8] = {};
    for (int l = 0; l < LL; ++l) {
        const float* er = enc_out + (size_t)l * (BB * 256) + (size_t)b0 * 256 + tid;
        #pragma unroll
        for (int r = 0; r < 8; ++r) acc[r] += al_s[r * 100 + l] * er[r * 256];
    }
    for (int r = 0; r < 8; ++r) ctx[(size_t)(b0 + r) * 256 + tid] = acc[r];
}

// ---------------------------------------------------------------------------
// Decoder LSTM cell (round-8 structure): grid 256 x 512, block = 8 rows,
// col-pair weights from col-pair chunk-major Wre. hd updated in place.
// ---------------------------------------------------------------------------
__global__ __launch_bounds__(512) void dec_step(
    const float* __restrict__ ctxp, const float* __restrict__ Wre,
    const float* __restrict__ bdec,
    float* __restrict__ hd, float* __restrict__ c_st, int first)
{
    __shared__ float ct_s[8 * 256];
    __shared__ float hd_s[8 * 256];
    __shared__ float gate_s[8 * 1024];
    const int row0 = blockIdx.x * 8;
    const int tid  = threadIdx.x;
    const int lane = tid & 63, w = tid >> 6;

    ((float4*)ct_s)[tid] = ((const float4*)(ctxp + (size_t)row0 * 256))[tid];
    if (!first)
        ((float4*)hd_s)[tid] = ((const float4*)(hd + (size_t)row0 * 256))[tid];
    __syncthreads();

    float2 acc2[8];
    {
        const float2 be2 = *(const float2*)&bdec[2 * tid];
        #pragma unroll
        for (int r = 0; r < 8; ++r) acc2[r] = be2;
    }
    const float* wp = Wre + (size_t)tid * 8;
    #pragma unroll 4
    for (int ch = 0; ch < 64; ++ch) {
        float4 w0 = *(const float4*)&wp[0];
        float4 w1 = *(const float4*)&wp[4];
        wp += 4096;
        float4 cv[8];
        #pragma unroll
        for (int r = 0; r < 8; ++r) cv[r] = *(const float4*)&ct_s[r * 256 + ch * 4];
        #pragma unroll
        for (int kk = 0; kk < 4; ++kk) {
            float wv0 = COMP(w0, kk), wv1 = COMP(w1, kk);
            #pragma unroll
            for (int r = 0; r < 8; ++r) {
                float e = COMP(cv[r], kk);
                acc2[r].x += e * wv0; acc2[r].y += e * wv1;
            }
        }
    }
    if (!first) {
        #pragma unroll 4
        for (int ch = 0; ch < 64; ++ch) {
            float4 w0 = *(const float4*)&wp[0];
            float4 w1 = *(const float4*)&wp[4];
            wp += 4096;
            float4 hv[8];
            #pragma unroll
            for (int r = 0; r < 8; ++r) hv[r] = *(const float4*)&hd_s[r * 256 + ch * 4];
            #pragma unroll
            for (int kk = 0; kk < 4; ++kk) {
                float wv0 = COMP(w0, kk), wv1 = COMP(w1, kk);
                #pragma unroll
                for (int r = 0; r < 8; ++r) {
                    float e = COMP(hv[r], kk);
                    acc2[r].x += e * wv0; acc2[r].y += e * wv1;
                }
            }
        }
    }
    #pragma unroll
    for (int r = 0; r < 8; ++r) *(float2*)&gate_s[r * 1024 + 2 * tid] = acc2[r];
    __syncthreads();

    {
        float4 gi4 = *(const float4*)&gate_s[w * 1024 +       lane * 4];
        float4 gf4 = *(const float4*)&gate_s[w * 1024 + 256 + lane * 4];
        float4 gg4 = *(const float4*)&gate_s[w * 1024 + 512 + lane * 4];
        float4 go4 = *(const float4*)&gate_s[w * 1024 + 768 + lane * 4];
        size_t ci = (size_t)(row0 + w) * 256 + lane * 4;
        float4 c4 = first ? make_float4(0.f, 0.f, 0.f, 0.f)
                          : *(const float4*)&c_st[ci];
        float4 cn, hn;
        cn.x = sigmoidf_(gf4.x) * c4.x + sigmoidf_(gi4.x) * tanhf_(gg4.x);
        hn.x = sigmoidf_(go4.x) * tanhf_(cn.x);
        cn.y = sigmoidf_(gf4.y) * c4.y + sigmoidf_(gi4.y) * tanhf_(gg4.y);
        hn.y = sigmoidf_(go4.y) * tanhf_(cn.y);
        cn.z = sigmoidf_(gf4.z) * c4.z + sigmoidf_(gi4.z) * tanhf_(gg4.z);
        hn.z = sigmoidf_(go4.z) * tanhf_(cn.z);
        cn.w = sigmoidf_(gf4.w) * c4.w + sigmoidf_(gi4.w) * tanhf_(gg4.w);
        hn.w = sigmoidf_(go4.w) * tanhf_(cn.w);
        *(float4*)&c_st[ci] = cn;
        *(float4*)&hd[ci]   = hn;
    }
}

// ---------------------------------------------------------------------------
// Head: fc = tanh(h_d@Wf+bf); out[:,step] = tanh(fc@Wo+bo). Block = 16 rows.
// ---------------------------------------------------------------------------
__global__ __launch_bounds__(256) void head_k(
    const float* __restrict__ hd, const float* __restrict__ Wf,
    const float* __restrict__ bf, const float* __restrict__ Wo,
    const float* __restrict__ bo, float* __restrict__ out, int step)
{
    __shared__ float hd_s[16 * 256];
    __shared__ float fc_s[16 * 128];
    const int b0  = blockIdx.x * 16;
    const int tid = threadIdx.x;
    {
        const float4* hg = (const float4*)(hd + (size_t)b0 * 256);
        for (int i = tid; i < 1024; i += 256) ((float4*)hd_s)[i] = hg[i];
    }
    __syncthreads();
    {
        const int f = tid & 127, rg = tid >> 7;
        float acc[8];
        float bfv = bf[f];
        #pragma unroll
        for (int rr = 0; rr < 8; ++rr) acc[rr] = bfv;
        const float* wp = Wf + f;
        #pragma unroll 2
        for (int k = 0; k < 256; ++k) {
            float wv = wp[k * 128];
            #pragma unroll
            for (int rr = 0; rr < 8; ++rr) acc[rr] += hd_s[(rg * 8 + rr) * 256 + k] * wv;
        }
        for (int rr = 0; rr < 8; ++rr) fc_s[(rg * 8 + rr) * 128 + f] = tanhf_(acc[rr]);
    }
    __syncthreads();
    {
        const int lane = tid & 63, w = tid >> 6;
        const float bov = bo[0];
        #pragma unroll
        for (int rr = 0; rr < 4; ++rr) {
            int r = w * 4 + rr;
            float p = fc_s[r * 128 + lane] * Wo[lane] + fc_s[r * 128 + 64 + lane] * Wo[64 + lane];
            #pragma unroll
            for (int msk = 32; msk >= 1; msk >>= 1) p += __shfl_xor(p, msk, 64);
            if (lane == 0) out[(size_t)(b0 + r) * NOUT + step] = tanhf_(p + bov);
        }
    }
}

extern "C" void kernel_launch(void* const* d_in, const int* in_sizes, int n_in,
                              void* d_out, int out_size, void* d_ws, size_t ws_size,
                              hipStream_t stream)
{
    const float* x    = (const float*)d_in[0];
    const float* Wa   = (const float*)d_in[1];
    const float* ba   = (const float*)d_in[2];
    const float* Wi   = (const float*)d_in[3];
    const float* Wh   = (const float*)d_in[4];
    const float* be   = (const float*)d_in[5];
    const float* Wd   = (const float*)d_in[6];
    const float* bd   = (const float*)d_in[7];
    const float* Wl   = (const float*)d_in[8];
    const float* bl   = (const float*)d_in[9];
    const float* Wdi  = (const float*)d_in[10];
    const float* Wdh  = (const float*)d_in[11];
    const float* bdec = (const float*)d_in[12];
    const float* Wf   = (const float*)d_in[13];
    const float* bf   = (const float*)d_in[14];
    const float* Wo   = (const float*)d_in[15];
    const float* bo   = (const float*)d_in[16];
    float* out = (float*)d_out;

    // ws layout (floats): enc_out | hd | c_d | ctx | scores | Wenc_re | Wdec_re | WaT
    // total 55,078,912 floats = 220.3 MB (ws >= 221 MB verified in round 2)
    const size_t f_enc    = (size_t)LL * BB * EE;     // 52,428,800
    const size_t f_state  = (size_t)BB * EE;          // 524,288
    const size_t f_scores = (size_t)LL * BB;          // 204,800
    const size_t f_wenc   = 320 * 1024;               // 327,680
    const size_t f_wdec   = 512 * 1024;               // 524,288
    const size_t f_wat    = 64 * 320;                 // 20,480
    const size_t need_f   = f_enc + 3 * f_state + f_scores + f_wenc + f_wdec + f_wat;

    float* ws      = (float*)d_ws;
    float* enc_out = ws;
    float* hd      = enc_out + f_enc;
    float* c_d     = hd + f_state;
    float* ctx     = c_d + f_state;
    float* scores  = ctx + f_state;
    float* Wenc_re = scores + f_scores;
    float* Wdec_re = Wenc_re + f_wenc;
    float* WaT     = Wdec_re + f_wdec;

    if (ws_size < need_f * sizeof(float)) return;   // diagnostic clean-fail

    // per-call weight re-layouts (tiny)
    wpack <<<(int)((f_wenc + 255) / 256), 256, 0, stream>>>(Wi, 64, Wh, Wenc_re, (int)f_wenc);
    wtrans<<<(int)((f_wdec + 255) / 256), 256, 0, stream>>>(Wdi, 256, Wdh, Wdec_re, (int)f_wdec);
    watrans<<<(int)((f_wat + 255) / 256), 256, 0, stream>>>(Wa, WaT);

    // persistent encoder: one dispatch for all 100 timesteps
    enc_all<<<BB / 8, 512, 0, stream>>>(x, WaT, ba, Wenc_re, be, enc_out);

    for (int s = 0; s < NOUT; ++s) {
        scores_fused<<<dim3(BB / 16, 5), 256, 0, stream>>>(
            enc_out, Wd, bd, Wl, bl, hd, scores, s == 0);
        softmax_ctx<<<BB / 8, 256, 0, stream>>>(scores, enc_out, ctx);
        dec_step<<<BB / 8, 512, 0, stream>>>(ctx, Wdec_re, bdec, hd, c_d, s == 0);
        head_k<<<BB / 16, 256, 0, stream>>>(hd, Wf, bf, Wo, bo, out, s);
    }
}

// Round 10
// 4812.357 us; speedup vs baseline: 1.4284x; 1.1539x over previous
//
#include <hip/hip_runtime.h>
#include <math.h>

// Problem constants
#define BB 2048
#define LL 100
#define FF 64
#define EE 256
#define DD 256
#define NOUT 3

#define COMP(v, i) ((i) == 0 ? (v).x : (i) == 1 ? (v).y : (i) == 2 ? (v).z : (v).w)

__device__ __forceinline__ float sigmoidf_(float x) {
    return 1.0f / (1.0f + expf(-x));
}
// tanh via identity 1 - 2/(1+e^{2x}); ~2e-7 abs fp32 error, saturates correctly.
__device__ __forceinline__ float tanhf_(float x) {
    return 1.0f - 2.0f / (1.0f + expf(2.0f * x));
}

// ---------------------------------------------------------------------------
// Persistent encoder. grid 256 x 512; block owns 8 rows; wave w <-> row w.
// Gates: thread = (half = tid>>8, ct = tid&255) -> cols ct*4..+3 read DIRECTLY
// from row-major Wi/Wh as lane-contiguous float4 (wave = 256 contiguous cols
// = 1KB coalesced per instruction); k-split halves (160 k each) combined via
// gate_s[2]. One LDS activation broadcast (b128) feeds 16 FMAs.
// Attention: wave w -> row w, lane = col; scalar Wa loads (lane-contiguous,
// coalesced). 2 barriers/step.
// ---------------------------------------------------------------------------
__global__ __launch_bounds__(512) void enc_all(
    const float* __restrict__ x,
    const float* __restrict__ Wa, const float* __restrict__ ba,
    const float* __restrict__ Wi, const float* __restrict__ Wh,
    const float* __restrict__ be,
    float* __restrict__ enc_out)
{
    __shared__ float act_s[8 * 320];       // 10 KB [row][0:64 ein | 64:320 h]
    __shared__ float x_s[8 * 64];          // 2 KB
    __shared__ float gate_s[2][8 * 1024];  // 64 KB partial-sum halves

    const int row0 = blockIdx.x * 8;
    const int tid  = threadIdx.x;
    const int lane = tid & 63;
    const int w    = tid >> 6;       // wave 0..7 == row
    const int half = tid >> 8;       // k-split half (wave-uniform)
    const int ct   = tid & 255;      // col-quad owner
    const int c0   = ct * 4;

    float4 bias4;
    {
        float4 b4 = *(const float4*)&be[c0];
        bias4 = (half == 0) ? b4 : make_float4(0.f, 0.f, 0.f, 0.f);
    }
    const float  bav  = ba[lane];
    const float* xrow = x + (size_t)(row0 + w) * LL * FF;
    const float* wiP  = Wi + c0;
    const float* whP  = Wh + c0;
    float c_reg[4] = {0.f, 0.f, 0.f, 0.f};

    for (int t = 0; t < LL; ++t) {
        // stage x_t row w (wave-local)
        x_s[w * 64 + lane] = xrow[t * FF + lane];

        // ---- input attention: wave w -> row w, lane -> col (coalesced Wa) ----
        {
            float a = bav;
            #pragma unroll 4
            for (int k4 = 0; k4 < 64; k4 += 4) {
                float4 xa = *(const float4*)&x_s[w * 64 + k4];
                a += xa.x * Wa[(k4 + 0) * 64 + lane]
                   + xa.y * Wa[(k4 + 1) * 64 + lane]
                   + xa.z * Wa[(k4 + 2) * 64 + lane]
                   + xa.w * Wa[(k4 + 3) * 64 + lane];
            }
            if (t > 0) {
                #pragma unroll 4
                for (int k4 = 64; k4 < 320; k4 += 4) {
                    float4 ha = *(const float4*)&act_s[w * 320 + k4];
                    a += ha.x * Wa[(k4 + 0) * 64 + lane]
                       + ha.y * Wa[(k4 + 1) * 64 + lane]
                       + ha.z * Wa[(k4 + 2) * 64 + lane]
                       + ha.w * Wa[(k4 + 3) * 64 + lane];
                }
            }
            float e = tanhf_(a);
            float m = e;
            #pragma unroll
            for (int msk = 32; msk >= 1; msk >>= 1) m = fmaxf(m, __shfl_xor(m, msk, 64));
            float ev = expf(e - m);
            float s = ev;
            #pragma unroll
            for (int msk = 32; msk >= 1; msk >>= 1) s += __shfl_xor(s, msk, 64);
            act_s[w * 320 + lane] = (ev / s) * x_s[w * 64 + lane];
        }
        __syncthreads();   // sync1: ein + prev-h visible to all waves

        // ---- gates: thread -> 4 cols, half k-range, 8 rows ----
        float4 acc[8];
        #pragma unroll
        for (int r = 0; r < 8; ++r) acc[r] = bias4;

        if (half == 0) {
            // k = 0..63: ein @ Wi
            #pragma unroll 2
            for (int ch = 0; ch < 16; ++ch) {
                const int k0 = ch * 4;
                float4 w0 = *(const float4*)&wiP[(size_t)(k0 + 0) * 1024];
                float4 w1 = *(const float4*)&wiP[(size_t)(k0 + 1) * 1024];
                float4 w2 = *(const float4*)&wiP[(size_t)(k0 + 2) * 1024];
                float4 w3 = *(const float4*)&wiP[(size_t)(k0 + 3) * 1024];
                #pragma unroll
                for (int r = 0; r < 8; ++r) {
                    float4 av = *(const float4*)&act_s[r * 320 + k0];
                    acc[r].x += av.x * w0.x; acc[r].y += av.x * w0.y;
                    acc[r].z += av.x * w0.z; acc[r].w += av.x * w0.w;
                    acc[r].x += av.y * w1.x; acc[r].y += av.y * w1.y;
                    acc[r].z += av.y * w1.z; acc[r].w += av.y * w1.w;
                    acc[r].x += av.z * w2.x; acc[r].y += av.z * w2.y;
                    acc[r].z += av.z * w2.z; acc[r].w += av.z * w2.w;
                    acc[r].x += av.w * w3.x; acc[r].y += av.w * w3.y;
                    acc[r].z += av.w * w3.z; acc[r].w += av.w * w3.w;
                }
            }
            if (t > 0) {
                // h rows 0..95 of Wh (global k = 64..159)
                #pragma unroll 2
                for (int ch = 0; ch < 24; ++ch) {
                    const int hk = ch * 4;
                    float4 w0 = *(const float4*)&whP[(size_t)(hk + 0) * 1024];
                    float4 w1 = *(const float4*)&whP[(size_t)(hk + 1) * 1024];
                    float4 w2 = *(const float4*)&whP[(size_t)(hk + 2) * 1024];
                    float4 w3 = *(const float4*)&whP[(size_t)(hk + 3) * 1024];
                    #pragma unroll
                    for (int r = 0; r < 8; ++r) {
                        float4 av = *(const float4*)&act_s[r * 320 + 64 + hk];
                        acc[r].x += av.x * w0.x; acc[r].y += av.x * w0.y;
                        acc[r].z += av.x * w0.z; acc[r].w += av.x * w0.w;
                        acc[r].x += av.y * w1.x; acc[r].y += av.y * w1.y;
                        acc[r].z += av.y * w1.z; acc[r].w += av.y * w1.w;
                        acc[r].x += av.z * w2.x; acc[r].y += av.z * w2.y;
                        acc[r].z += av.z * w2.z; acc[r].w += av.z * w2.w;
                        acc[r].x += av.w * w3.x; acc[r].y += av.w * w3.y;
                        acc[r].z += av.w * w3.z; acc[r].w += av.w * w3.w;
                    }
                }
            }
        } else if (t > 0) {
            // h rows 96..255 of Wh (global k = 160..319)
            #pragma unroll 2
            for (int ch = 0; ch < 40; ++ch) {
                const int hk = 96 + ch * 4;
                float4 w0 = *(const float4*)&whP[(size_t)(hk + 0) * 1024];
                float4 w1 = *(const float4*)&whP[(size_t)(hk + 1) * 1024];
                float4 w2 = *(const float4*)&whP[(size_t)(hk + 2) * 1024];
                float4 w3 = *(const float4*)&whP[(size_t)(hk + 3) * 1024];
                #pragma unroll
                for (int r = 0; r < 8; ++r) {
                    float4 av = *(const float4*)&act_s[r * 320 + 64 + hk];
                    acc[r].x += av.x * w0.x; acc[r].y += av.x * w0.y;
                    acc[r].z += av.x * w0.z; acc[r].w += av.x * w0.w;
                    acc[r].x += av.y * w1.x; acc[r].y += av.y * w1.y;
                    acc[r].z += av.y * w1.z; acc[r].w += av.y * w1.w;
                    acc[r].x += av.z * w2.x; acc[r].y += av.z * w2.y;
                    acc[r].z += av.z * w2.z; acc[r].w += av.z * w2.w;
                    acc[r].x += av.w * w3.x; acc[r].y += av.w * w3.y;
                    acc[r].z += av.w * w3.z; acc[r].w += av.w * w3.w;
                }
            }
        }
        #pragma unroll
        for (int r = 0; r < 8; ++r)
            *(float4*)&gate_s[half][r * 1024 + c0] = acc[r];
        __syncthreads();   // sync2: both halves staged; all act reads complete

        // ---- epilogue: wave-local. lane -> units lane*4..+3 of row w ----
        {
            const float* g0 = &gate_s[0][w * 1024 + lane * 4];
            const float* g1 = &gate_s[1][w * 1024 + lane * 4];
            float4 giA = *(const float4*)&g0[0],   giB = *(const float4*)&g1[0];
            float4 gfA = *(const float4*)&g0[256], gfB = *(const float4*)&g1[256];
            float4 ggA = *(const float4*)&g0[512], ggB = *(const float4*)&g1[512];
            float4 goA = *(const float4*)&g0[768], goB = *(const float4*)&g1[768];
            float gi[4] = { giA.x + giB.x, giA.y + giB.y, giA.z + giB.z, giA.w + giB.w };
            float gf[4] = { gfA.x + gfB.x, gfA.y + gfB.y, gfA.z + gfB.z, gfA.w + gfB.w };
            float gg[4] = { ggA.x + ggB.x, ggA.y + ggB.y, ggA.z + ggB.z, ggA.w + ggB.w };
            float go[4] = { goA.x + goB.x, goA.y + goB.y, goA.z + goB.z, goA.w + goB.w };
            float4 hn;
            #pragma unroll
            for (int uu = 0; uu < 4; ++uu) {
                float cn = sigmoidf_(gf[uu]) * c_reg[uu] + sigmoidf_(gi[uu]) * tanhf_(gg[uu]);
                c_reg[uu] = cn;
                float hv = sigmoidf_(go[uu]) * tanhf_(cn);
                if (uu == 0) hn.x = hv; else if (uu == 1) hn.y = hv;
                else if (uu == 2) hn.z = hv; else hn.w = hv;
            }
            *(float4*)&act_s[w * 320 + 64 + lane * 4] = hn;
            *(float4*)&enc_out[((size_t)t * BB + row0 + w) * 256 + lane * 4] = hn;
        }
        // no 3rd barrier: next attention reads only wave-local act_s/x_s;
        // cross-wave reads are guarded by the next sync1.
    }
}

// ---------------------------------------------------------------------------
// Fused decoder attention scores, Lin=2. grid (B/16, 5), 256 threads.
// ---------------------------------------------------------------------------
#define SC_LIN 2
__global__ __launch_bounds__(256) void scores_fused(
    const float* __restrict__ enc_out, const float* __restrict__ Wd,
    const float* __restrict__ bd,
    const float* __restrict__ Wl, const float* __restrict__ bl,
    const float* __restrict__ hd, float* __restrict__ scores, int first)
{
    __shared__ float enc_s[SC_LIN * 16 * 256];   // 32 KB
    const int b0   = blockIdx.x * 16;
    const int l0   = blockIdx.y * 20;
    const int tid  = threadIdx.x;
    const int lane = tid & 63;
    const int rg   = tid >> 6;
    const int n0   = lane * 4;

    float hdp[4][4];
    {
        float4 bd4 = *(const float4*)&bd[n0];
        #pragma unroll
        for (int r = 0; r < 4; ++r) {
            hdp[r][0] = bd4.x; hdp[r][1] = bd4.y; hdp[r][2] = bd4.z; hdp[r][3] = bd4.w;
        }
    }
    if (!first) {
        for (int v = tid; v < 1024; v += 256) {
            int r = v >> 6, qq = v & 63;
            *(float4*)&enc_s[r * 256 + qq * 4] =
                *(const float4*)(hd + (size_t)(b0 + r) * 256 + qq * 4);
        }
        __syncthreads();
        const float* wb = Wd + 256 * 256;
        #pragma unroll 2
        for (int k = 0; k < 256; k += 4) {
            float4 hv[4];
            #pragma unroll
            for (int r = 0; r < 4; ++r) hv[r] = *(const float4*)&enc_s[(rg * 4 + r) * 256 + k];
            #pragma unroll
            for (int kk = 0; kk < 4; ++kk) {
                float4 wv = *(const float4*)&wb[(size_t)(k + kk) * 256 + n0];
                #pragma unroll
                for (int r = 0; r < 4; ++r) {
                    float e = COMP(hv[r], kk);
                    hdp[r][0] += e * wv.x; hdp[r][1] += e * wv.y;
                    hdp[r][2] += e * wv.z; hdp[r][3] += e * wv.w;
                }
            }
        }
        __syncthreads();
    }
    float4 wl4 = *(const float4*)&Wl[n0];
    const float blv = bl[0];

    for (int lo = 0; lo < 20; lo += SC_LIN) {
        for (int v = tid; v < SC_LIN * 16 * 64; v += 256) {
            int li = v >> 10, rem = v & 1023;
            int r = rem >> 6, qq = rem & 63;
            *(float4*)&enc_s[li * 4096 + r * 256 + qq * 4] =
                *(const float4*)(enc_out + (size_t)(l0 + lo + li) * (BB * 256)
                                 + (size_t)(b0 + r) * 256 + qq * 4);
        }
        __syncthreads();

        float acc[SC_LIN][4][4];
        #pragma unroll
        for (int li = 0; li < SC_LIN; ++li)
            #pragma unroll
            for (int r = 0; r < 4; ++r)
                #pragma unroll
                for (int c = 0; c < 4; ++c) acc[li][r][c] = hdp[r][c];

        for (int k = 0; k < 256; k += 4) {
            float4 wv[4];
            #pragma unroll
            for (int kk = 0; kk < 4; ++kk)
                wv[kk] = *(const float4*)&Wd[(size_t)(k + kk) * 256 + n0];
            #pragma unroll
            for (int li = 0; li < SC_LIN; ++li) {
                float4 ev[4];
                #pragma unroll
                for (int r = 0; r < 4; ++r)
                    ev[r] = *(const float4*)&enc_s[li * 4096 + (rg * 4 + r) * 256 + k];
                #pragma unroll
                for (int kk = 0; kk < 4; ++kk) {
                    #pragma unroll
                    for (int r = 0; r < 4; ++r) {
                        float e = COMP(ev[r], kk);
                        acc[li][r][0] += e * wv[kk].x; acc[li][r][1] += e * wv[kk].y;
                        acc[li][r][2] += e * wv[kk].z; acc[li][r][3] += e * wv[kk].w;
                    }
                }
            }
        }
        #pragma unroll
        for (int li = 0; li < SC_LIN; ++li) {
            #pragma unroll
            for (int r = 0; r < 4; ++r) {
                float p = tanhf_(acc[li][r][0]) * wl4.x + tanhf_(acc[li][r][1]) * wl4.y
                        + tanhf_(acc[li][r][2]) * wl4.z + tanhf_(acc[li][r][3]) * wl4.w;
                #pragma unroll
                for (int msk = 32; msk >= 1; msk >>= 1) p += __shfl_xor(p, msk, 64);
                if (lane == 0)
                    scores[(size_t)(l0 + lo + li) * BB + b0 + rg * 4 + r] = p + blv;
            }
        }
        __syncthreads();
    }
}

// ---------------------------------------------------------------------------
// softmax over L + ctx from scores buffer. Block = 8 rows.
// ---------------------------------------------------------------------------
__global__ __launch_bounds__(256) void softmax_ctx(
    const float* __restrict__ scores, const float* __restrict__ enc_out,
    float* __restrict__ ctx)
{
    __shared__ float al_s[8 * 100];
    const int b0  = blockIdx.x * 8;
    const int tid = threadIdx.x;
    for (int v = tid; v < 800; v += 256) {
        int r = v / 100, l = v - r * 100;
        al_s[r * 100 + l] = scores[(size_t)l * BB + b0 + r];
    }
    __syncthreads();
    if (tid < 8) {
        float m = -1e30f;
        for (int l = 0; l < LL; ++l) m = fmaxf(m, al_s[tid * 100 + l]);
        float s = 0.f;
        for (int l = 0; l < LL; ++l) { float e = expf(al_s[tid * 100 + l] - m); al_s[tid * 100 + l] = e; s += e; }
        float inv = 1.f / s;
        for (int l = 0; l < LL; ++l) al_s[tid * 100 + l] *= inv;
    }
    __syncthreads();
    float acc[8] = {};
    for (int l = 0; l < LL; ++l) {
        const float* er = enc_out + (size_t)l * (BB * 256) + (size_t)b0 * 256 + tid;
        #pragma unroll
        for (int r = 0; r < 8; ++r) acc[r] += al_s[r * 100 + l] * er[r * 256];
    }
    for (int r = 0; r < 8; ++r) ctx[(size_t)(b0 + r) * 256 + tid] = acc[r];
}

// ---------------------------------------------------------------------------
// Decoder LSTM cell, enc_all gate structure: grid 256 x 512, block = 8 rows,
// half0 = ctx@Wdi, half1 = hd@Wdh, coalesced float4 weight loads from the
// original row-major matrices. hd updated in place.
// ---------------------------------------------------------------------------
__global__ __launch_bounds__(512) void dec_step(
    const float* __restrict__ ctxp,
    const float* __restrict__ Wdi, const float* __restrict__ Wdh,
    const float* __restrict__ bdec,
    float* __restrict__ hd, float* __restrict__ c_st, int first)
{
    __shared__ float ct_s[8 * 256];        // 8 KB
    __shared__ float hd_s[8 * 256];        // 8 KB
    __shared__ float gate_s[2][8 * 1024];  // 64 KB
    const int row0 = blockIdx.x * 8;
    const int tid  = threadIdx.x;
    const int lane = tid & 63, w = tid >> 6;
    const int half = tid >> 8;
    const int ct   = tid & 255;
    const int c0   = ct * 4;

    ((float4*)ct_s)[tid] = ((const float4*)(ctxp + (size_t)row0 * 256))[tid];
    if (!first)
        ((float4*)hd_s)[tid] = ((const float4*)(hd + (size_t)row0 * 256))[tid];
    __syncthreads();

    float4 acc[8];
    {
        float4 b4 = *(const float4*)&bdec[c0];
        float4 bias4 = (half == 0) ? b4 : make_float4(0.f, 0.f, 0.f, 0.f);
        #pragma unroll
        for (int r = 0; r < 8; ++r) acc[r] = bias4;
    }
    if (half == 0) {
        const float* wP = Wdi + c0;
        #pragma unroll 2
        for (int ch = 0; ch < 64; ++ch) {
            const int k0 = ch * 4;
            float4 w0 = *(const float4*)&wP[(size_t)(k0 + 0) * 1024];
            float4 w1 = *(const float4*)&wP[(size_t)(k0 + 1) * 1024];
            float4 w2 = *(const float4*)&wP[(size_t)(k0 + 2) * 1024];
            float4 w3 = *(const float4*)&wP[(size_t)(k0 + 3) * 1024];
            #pragma unroll
            for (int r = 0; r < 8; ++r) {
                float4 av = *(const float4*)&ct_s[r * 256 + k0];
                acc[r].x += av.x * w0.x; acc[r].y += av.x * w0.y;
                acc[r].z += av.x * w0.z; acc[r].w += av.x * w0.w;
                acc[r].x += av.y * w1.x; acc[r].y += av.y * w1.y;
                acc[r].z += av.y * w1.z; acc[r].w += av.y * w1.w;
                acc[r].x += av.z * w2.x; acc[r].y += av.z * w2.y;
                acc[r].z += av.z * w2.z; acc[r].w += av.z * w2.w;
                acc[r].x += av.w * w3.x; acc[r].y += av.w * w3.y;
                acc[r].z += av.w * w3.z; acc[r].w += av.w * w3.w;
            }
        }
    } else if (!first) {
        const float* wP = Wdh + c0;
        #pragma unroll 2
        for (int ch = 0; ch < 64; ++ch) {
            const int k0 = ch * 4;
            float4 w0 = *(const float4*)&wP[(size_t)(k0 + 0) * 1024];
            float4 w1 = *(const float4*)&wP[(size_t)(k0 + 1) * 1024];
            float4 w2 = *(const float4*)&wP[(size_t)(k0 + 2) * 1024];
            float4 w3 = *(const float4*)&wP[(size_t)(k0 + 3) * 1024];
            #pragma unroll
            for (int r = 0; r < 8; ++r) {
                float4 av = *(const float4*)&hd_s[r * 256 + k0];
                acc[r].x += av.x * w0.x; acc[r].y += av.x * w0.y;
                acc[r].z += av.x * w0.z; acc[r].w += av.x * w0.w;
                acc[r].x += av.y * w1.x; acc[r].y += av.y * w1.y;
                acc[r].z += av.y * w1.z; acc[r].w += av.y * w1.w;
                acc[r].x += av.z * w2.x; acc[r].y += av.z * w2.y;
                acc[r].z += av.z * w2.z; acc[r].w += av.z * w2.w;
                acc[r].x += av.w * w3.x; acc[r].y += av.w * w3.y;
                acc[r].z += av.w * w3.z; acc[r].w += av.w * w3.w;
            }
        }
    }
    #pragma unroll
    for (int r = 0; r < 8; ++r)
        *(float4*)&gate_s[half][r * 1024 + c0] = acc[r];
    __syncthreads();

    // epilogue: wave-local row w, lane -> 4 units
    {
        const float* g0 = &gate_s[0][w * 1024 + lane * 4];
        const float* g1 = &gate_s[1][w * 1024 + lane * 4];
        float4 giA = *(const float4*)&g0[0],   giB = *(const float4*)&g1[0];
        float4 gfA = *(const float4*)&g0[256], gfB = *(const float4*)&g1[256];
        float4 ggA = *(const float4*)&g0[512], ggB = *(const float4*)&g1[512];
        float4 goA = *(const float4*)&g0[768], goB = *(const float4*)&g1[768];
        size_t ci = (size_t)(row0 + w) * 256 + lane * 4;
        float4 c4 = first ? make_float4(0.f, 0.f, 0.f, 0.f)
                          : *(const float4*)&c_st[ci];
        float cc[4] = { c4.x, c4.y, c4.z, c4.w };
        float gi[4] = { giA.x + giB.x, giA.y + giB.y, giA.z + giB.z, giA.w + giB.w };
        float gf[4] = { gfA.x + gfB.x, gfA.y + gfB.y, gfA.z + gfB.z, gfA.w + gfB.w };
        float gg[4] = { ggA.x + ggB.x, ggA.y + ggB.y, ggA.z + ggB.z, ggA.w + ggB.w };
        float go[4] = { goA.x + goB.x, goA.y + goB.y, goA.z + goB.z, goA.w + goB.w };
        float4 cn, hn;
        #pragma unroll
        for (int uu = 0; uu < 4; ++uu) {
            float cv = sigmoidf_(gf[uu]) * cc[uu] + sigmoidf_(gi[uu]) * tanhf_(gg[uu]);
            float hv = sigmoidf_(go[uu]) * tanhf_(cv);
            if (uu == 0) { cn.x = cv; hn.x = hv; } else if (uu == 1) { cn.y = cv; hn.y = hv; }
            else if (uu == 2) { cn.z = cv; hn.z = hv; } else { cn.w = cv; hn.w = hv; }
        }
        *(float4*)&c_st[ci] = cn;
        *(float4*)&hd[ci]   = hn;
    }
}

// ---------------------------------------------------------------------------
// Head: fc = tanh(h_d@Wf+bf); out[:,step] = tanh(fc@Wo+bo). Block = 16 rows.
// ---------------------------------------------------------------------------
__global__ __launch_bounds__(256) void head_k(
    const float* __restrict__ hd, const float* __restrict__ Wf,
    const float* __restrict__ bf, const float* __restrict__ Wo,
    const float* __restrict__ bo, float* __restrict__ out, int step)
{
    __shared__ float hd_s[16 * 256];
    __shared__ float fc_s[16 * 128];
    const int b0  = blockIdx.x * 16;
    const int tid = threadIdx.x;
    {
        const float4* hg = (const float4*)(hd + (size_t)b0 * 256);
        for (int i = tid; i < 1024; i += 256) ((float4*)hd_s)[i] = hg[i];
    }
    __syncthreads();
    {
        const int f = tid & 127, rg = tid >> 7;
        float acc[8];
        float bfv = bf[f];
        #pragma unroll
        for (int rr = 0; rr < 8; ++rr) acc[rr] = bfv;
        const float* wp = Wf + f;
        #pragma unroll 2
        for (int k = 0; k < 256; ++k) {
            float wv = wp[k * 128];
            #pragma unroll
            for (int rr = 0; rr < 8; ++rr) acc[rr] += hd_s[(rg * 8 + rr) * 256 + k] * wv;
        }
        for (int rr = 0; rr < 8; ++rr) fc_s[(rg * 8 + rr) * 128 + f] = tanhf_(acc[rr]);
    }
    __syncthreads();
    {
        const int lane = tid & 63, w = tid >> 6;
        const float bov = bo[0];
        #pragma unroll
        for (int rr = 0; rr < 4; ++rr) {
            int r = w * 4 + rr;
            float p = fc_s[r * 128 + lane] * Wo[lane] + fc_s[r * 128 + 64 + lane] * Wo[64 + lane];
            #pragma unroll
            for (int msk = 32; msk >= 1; msk >>= 1) p += __shfl_xor(p, msk, 64);
            if (lane == 0) out[(size_t)(b0 + r) * NOUT + step] = tanhf_(p + bov);
        }
    }
}

extern "C" void kernel_launch(void* const* d_in, const int* in_sizes, int n_in,
                              void* d_out, int out_size, void* d_ws, size_t ws_size,
                              hipStream_t stream)
{
    const float* x    = (const float*)d_in[0];
    const float* Wa   = (const float*)d_in[1];
    const float* ba   = (const float*)d_in[2];
    const float* Wi   = (const float*)d_in[3];
    const float* Wh   = (const float*)d_in[4];
    const float* be   = (const float*)d_in[5];
    const float* Wd   = (const float*)d_in[6];
    const float* bd   = (const float*)d_in[7];
    const float* Wl   = (const float*)d_in[8];
    const float* bl   = (const float*)d_in[9];
    const float* Wdi  = (const float*)d_in[10];
    const float* Wdh  = (const float*)d_in[11];
    const float* bdec = (const float*)d_in[12];
    const float* Wf   = (const float*)d_in[13];
    const float* bf   = (const float*)d_in[14];
    const float* Wo   = (const float*)d_in[15];
    const float* bo   = (const float*)d_in[16];
    float* out = (float*)d_out;

    // ws layout (floats): enc_out | hd | c_d | ctx | scores  (~216.8 MB)
    const size_t f_enc    = (size_t)LL * BB * EE;     // 52,428,800
    const size_t f_state  = (size_t)BB * EE;          // 524,288
    const size_t f_scores = (size_t)LL * BB;          // 204,800
    const size_t need_f   = f_enc + 3 * f_state + f_scores;

    float* ws      = (float*)d_ws;
    float* enc_out = ws;
    float* hd      = enc_out + f_enc;
    float* c_d     = hd + f_state;
    float* ctx     = c_d + f_state;
    float* scores  = ctx + f_state;

    if (ws_size < need_f * sizeof(float)) return;   // diagnostic clean-fail

    // persistent encoder: one dispatch for all 100 timesteps
    enc_all<<<BB / 8, 512, 0, stream>>>(x, Wa, ba, Wi, Wh, be, enc_out);

    for (int s = 0; s < NOUT; ++s) {
        scores_fused<<<dim3(BB / 16, 5), 256, 0, stream>>>(
            enc_out, Wd, bd, Wl, bl, hd, scores, s == 0);
        softmax_ctx<<<BB / 8, 256, 0, stream>>>(scores, enc_out, ctx);
        dec_step<<<BB / 8, 512, 0, stream>>>(ctx, Wdi, Wdh, bdec, hd, c_d, s == 0);
        head_k<<<BB / 16, 256, 0, stream>>>(hd, Wf, bf, Wo, bo, out, s);
    }
}

// Round 11
// 4416.845 us; speedup vs baseline: 1.5563x; 1.0895x over previous
//
#include <hip/hip_runtime.h>
#include <math.h>

// Problem constants
#define BB 2048
#define LL 100
#define FF 64
#define EE 256
#define DD 256
#define NOUT 3

#define COMP(v, i) ((i) == 0 ? (v).x : (i) == 1 ? (v).y : (i) == 2 ? (v).z : (v).w)

__device__ __forceinline__ float sigmoidf_(float x) {
    return 1.0f / (1.0f + expf(-x));
}
// tanh via identity 1 - 2/(1+e^{2x}); ~2e-7 abs fp32 error, saturates correctly.
__device__ __forceinline__ float tanhf_(float x) {
    return 1.0f - 2.0f / (1.0f + expf(2.0f * x));
}

// ---------------------------------------------------------------------------
// Persistent encoder, 1024-thread blocks (16 waves -> 4 waves/SIMD at 1
// block/CU) with 4-way k-split. grid 256; block owns 8 rows for all 100 steps.
//  - attention: waves 0..7 (w = row), lane = col; coalesced scalar Wa loads.
//  - gates: thread = (quarter q = tid>>8, ct = tid&255) -> cols ct*4..+3,
//    k-chunks [q*20, q*20+20) of the stacked [Wi;Wh] (320 k total). Weights
//    read directly from row-major Wi/Wh as lane-contiguous float4 (1KB
//    coalesced per wave-inst). Per-CU weight traffic unchanged vs round 10
//    (same one block reads them once per step) -- only occupancy changes.
//  - partial combine: two phases through gate_s[2] (q0/q1 then q2/q3),
//    epilogue waves hold phase-1 partials in 16 regs. 4 barriers/step.
//  - epilogue: wave-local (w<8, lane -> 4 units of row w), c in registers.
// ---------------------------------------------------------------------------
__global__ __launch_bounds__(1024) void enc_all(
    const float* __restrict__ x,
    const float* __restrict__ Wa, const float* __restrict__ ba,
    const float* __restrict__ Wi, const float* __restrict__ Wh,
    const float* __restrict__ be,
    float* __restrict__ enc_out)
{
    __shared__ float act_s[8 * 320];       // 10 KB [row][0:64 ein | 64:320 h]
    __shared__ float x_s[8 * 64];          // 2 KB
    __shared__ float gate_s[2][8 * 1024];  // 64 KB two-quarter staging

    const int row0 = blockIdx.x * 8;
    const int tid  = threadIdx.x;
    const int lane = tid & 63;
    const int w    = tid >> 6;       // wave 0..15
    const int q    = tid >> 8;       // k-quarter 0..3 (wave-uniform)
    const int qq   = q & 1;          // staging slot within a phase
    const int ct   = tid & 255;      // col-quad owner
    const int c0   = ct * 4;
    const bool epi = (w < 8);        // attention + epilogue duty (== q<2)

    float4 bias4 = make_float4(0.f, 0.f, 0.f, 0.f);
    if (q == 0) bias4 = *(const float4*)&be[c0];
    const float  bav  = ba[lane];
    const float* xrow = x + (size_t)(row0 + (w & 7)) * LL * FF;
    const float* wiP  = Wi + c0;
    const float* whP  = Wh + c0;
    float c_reg[4] = {0.f, 0.f, 0.f, 0.f};

    for (int t = 0; t < LL; ++t) {
        // ---- attention: wave w (<8) -> row w, lane -> col (coalesced Wa) ----
        if (epi) {
            x_s[w * 64 + lane] = xrow[t * FF + lane];
            float a = bav;
            #pragma unroll 4
            for (int k4 = 0; k4 < 64; k4 += 4) {
                float4 xa = *(const float4*)&x_s[w * 64 + k4];
                a += xa.x * Wa[(k4 + 0) * 64 + lane]
                   + xa.y * Wa[(k4 + 1) * 64 + lane]
                   + xa.z * Wa[(k4 + 2) * 64 + lane]
                   + xa.w * Wa[(k4 + 3) * 64 + lane];
            }
            if (t > 0) {
                #pragma unroll 4
                for (int k4 = 64; k4 < 320; k4 += 4) {
                    float4 ha = *(const float4*)&act_s[w * 320 + k4];
                    a += ha.x * Wa[(k4 + 0) * 64 + lane]
                       + ha.y * Wa[(k4 + 1) * 64 + lane]
                       + ha.z * Wa[(k4 + 2) * 64 + lane]
                       + ha.w * Wa[(k4 + 3) * 64 + lane];
                }
            }
            float e = tanhf_(a);
            float m = e;
            #pragma unroll
            for (int msk = 32; msk >= 1; msk >>= 1) m = fmaxf(m, __shfl_xor(m, msk, 64));
            float ev = expf(e - m);
            float s = ev;
            #pragma unroll
            for (int msk = 32; msk >= 1; msk >>= 1) s += __shfl_xor(s, msk, 64);
            act_s[w * 320 + lane] = (ev / s) * x_s[w * 64 + lane];
        }
        __syncthreads();   // sync1: ein + prev-h visible; gate_s free to rewrite

        // ---- gates: quarter q -> chunks [q*20, q*20+20) over stacked k ----
        float4 acc[8];
        #pragma unroll
        for (int r = 0; r < 8; ++r) acc[r] = bias4;

        const int nch = (t == 0) ? (q == 0 ? 16 : 0) : 20;
        const int ch0 = q * 20;
        for (int c = 0; c < nch; ++c) {
            const int k0 = (ch0 + c) * 4;
            const float* wP = (k0 < 64) ? (wiP + (size_t)k0 * 1024)
                                        : (whP + (size_t)(k0 - 64) * 1024);
            float4 w0 = *(const float4*)&wP[0];
            float4 w1 = *(const float4*)&wP[1024];
            float4 w2 = *(const float4*)&wP[2048];
            float4 w3 = *(const float4*)&wP[3072];
            #pragma unroll
            for (int r = 0; r < 8; ++r) {
                float4 av = *(const float4*)&act_s[r * 320 + k0];
                acc[r].x += av.x * w0.x; acc[r].y += av.x * w0.y;
                acc[r].z += av.x * w0.z; acc[r].w += av.x * w0.w;
                acc[r].x += av.y * w1.x; acc[r].y += av.y * w1.y;
                acc[r].z += av.y * w1.z; acc[r].w += av.y * w1.w;
                acc[r].x += av.z * w2.x; acc[r].y += av.z * w2.y;
                acc[r].z += av.z * w2.z; acc[r].w += av.z * w2.w;
                acc[r].x += av.w * w3.x; acc[r].y += av.w * w3.y;
                acc[r].z += av.w * w3.z; acc[r].w += av.w * w3.w;
            }
        }
        // phase 1: quarters 0,1 stage
        if (q < 2) {
            #pragma unroll
            for (int r = 0; r < 8; ++r)
                *(float4*)&gate_s[qq][r * 1024 + c0] = acc[r];
        }
        __syncthreads();   // sync2: phase-1 staged

        float part[16];
        if (epi) {
            #pragma unroll
            for (int g = 0; g < 4; ++g) {
                float4 a4 = *(const float4*)&gate_s[0][w * 1024 + g * 256 + lane * 4];
                float4 b4 = *(const float4*)&gate_s[1][w * 1024 + g * 256 + lane * 4];
                part[g * 4 + 0] = a4.x + b4.x;
                part[g * 4 + 1] = a4.y + b4.y;
                part[g * 4 + 2] = a4.z + b4.z;
                part[g * 4 + 3] = a4.w + b4.w;
            }
        }
        __syncthreads();   // sync3: phase-1 consumed

        // phase 2: quarters 2,3 stage
        if (q >= 2) {
            #pragma unroll
            for (int r = 0; r < 8; ++r)
                *(float4*)&gate_s[qq][r * 1024 + c0] = acc[r];
        }
        __syncthreads();   // sync4: phase-2 staged

        // ---- epilogue: wave-local. lane -> units lane*4..+3 of row w ----
        if (epi) {
            #pragma unroll
            for (int g = 0; g < 4; ++g) {
                float4 a4 = *(const float4*)&gate_s[0][w * 1024 + g * 256 + lane * 4];
                float4 b4 = *(const float4*)&gate_s[1][w * 1024 + g * 256 + lane * 4];
                part[g * 4 + 0] += a4.x + b4.x;
                part[g * 4 + 1] += a4.y + b4.y;
                part[g * 4 + 2] += a4.z + b4.z;
                part[g * 4 + 3] += a4.w + b4.w;
            }
            float4 hn;
            #pragma unroll
            for (int uu = 0; uu < 4; ++uu) {
                float gi = part[0 + uu], gf = part[4 + uu];
                float gg = part[8 + uu], go = part[12 + uu];
                float cn = sigmoidf_(gf) * c_reg[uu] + sigmoidf_(gi) * tanhf_(gg);
                c_reg[uu] = cn;
                float hv = sigmoidf_(go) * tanhf_(cn);
                if (uu == 0) hn.x = hv; else if (uu == 1) hn.y = hv;
                else if (uu == 2) hn.z = hv; else hn.w = hv;
            }
            *(float4*)&act_s[w * 320 + 64 + lane * 4] = hn;
            *(float4*)&enc_out[((size_t)t * BB + row0 + w) * 256 + lane * 4] = hn;
        }
        // next-iter sync1 guards cross-wave act_s reads and gate_s reuse.
    }
}

// ---------------------------------------------------------------------------
// Fused decoder attention scores, Lin=2. grid (B/16, 5), 256 threads.
// ---------------------------------------------------------------------------
#define SC_LIN 2
__global__ __launch_bounds__(256) void scores_fused(
    const float* __restrict__ enc_out, const float* __restrict__ Wd,
    const float* __restrict__ bd,
    const float* __restrict__ Wl, const float* __restrict__ bl,
    const float* __restrict__ hd, float* __restrict__ scores, int first)
{
    __shared__ float enc_s[SC_LIN * 16 * 256];   // 32 KB
    const int b0   = blockIdx.x * 16;
    const int l0   = blockIdx.y * 20;
    const int tid  = threadIdx.x;
    const int lane = tid & 63;
    const int rg   = tid >> 6;
    const int n0   = lane * 4;

    float hdp[4][4];
    {
        float4 bd4 = *(const float4*)&bd[n0];
        #pragma unroll
        for (int r = 0; r < 4; ++r) {
            hdp[r][0] = bd4.x; hdp[r][1] = bd4.y; hdp[r][2] = bd4.z; hdp[r][3] = bd4.w;
        }
    }
    if (!first) {
        for (int v = tid; v < 1024; v += 256) {
            int r = v >> 6, qq = v & 63;
            *(float4*)&enc_s[r * 256 + qq * 4] =
                *(const float4*)(hd + (size_t)(b0 + r) * 256 + qq * 4);
        }
        __syncthreads();
        const float* wb = Wd + 256 * 256;
        #pragma unroll 2
        for (int k = 0; k < 256; k += 4) {
            float4 hv[4];
            #pragma unroll
            for (int r = 0; r < 4; ++r) hv[r] = *(const float4*)&enc_s[(rg * 4 + r) * 256 + k];
            #pragma unroll
            for (int kk = 0; kk < 4; ++kk) {
                float4 wv = *(const float4*)&wb[(size_t)(k + kk) * 256 + n0];
                #pragma unroll
                for (int r = 0; r < 4; ++r) {
                    float e = COMP(hv[r], kk);
                    hdp[r][0] += e * wv.x; hdp[r][1] += e * wv.y;
                    hdp[r][2] += e * wv.z; hdp[r][3] += e * wv.w;
                }
            }
        }
        __syncthreads();
    }
    float4 wl4 = *(const float4*)&Wl[n0];
    const float blv = bl[0];

    for (int lo = 0; lo < 20; lo += SC_LIN) {
        for (int v = tid; v < SC_LIN * 16 * 64; v += 256) {
            int li = v >> 10, rem = v & 1023;
            int r = rem >> 6, qq = rem & 63;
            *(float4*)&enc_s[li * 4096 + r * 256 + qq * 4] =
                *(const float4*)(enc_out + (size_t)(l0 + lo + li) * (BB * 256)
                                 + (size_t)(b0 + r) * 256 + qq * 4);
        }
        __syncthreads();

        float acc[SC_LIN][4][4];
        #pragma unroll
        for (int li = 0; li < SC_LIN; ++li)
            #pragma unroll
            for (int r = 0; r < 4; ++r)
                #pragma unroll
                for (int c = 0; c < 4; ++c) acc[li][r][c] = hdp[r][c];

        for (int k = 0; k < 256; k += 4) {
            float4 wv[4];
            #pragma unroll
            for (int kk = 0; kk < 4; ++kk)
                wv[kk] = *(const float4*)&Wd[(size_t)(k + kk) * 256 + n0];
            #pragma unroll
            for (int li = 0; li < SC_LIN; ++li) {
                float4 ev[4];
                #pragma unroll
                for (int r = 0; r < 4; ++r)
                    ev[r] = *(const float4*)&enc_s[li * 4096 + (rg * 4 + r) * 256 + k];
                #pragma unroll
                for (int kk = 0; kk < 4; ++kk) {
                    #pragma unroll
                    for (int r = 0; r < 4; ++r) {
                        float e = COMP(ev[r], kk);
                        acc[li][r][0] += e * wv[kk].x; acc[li][r][1] += e * wv[kk].y;
                        acc[li][r][2] += e * wv[kk].z; acc[li][r][3] += e * wv[kk].w;
                    }
                }
            }
        }
        #pragma unroll
        for (int li = 0; li < SC_LIN; ++li) {
            #pragma unroll
            for (int r = 0; r < 4; ++r) {
                float p = tanhf_(acc[li][r][0]) * wl4.x + tanhf_(acc[li][r][1]) * wl4.y
                        + tanhf_(acc[li][r][2]) * wl4.z + tanhf_(acc[li][r][3]) * wl4.w;
                #pragma unroll
                for (int msk = 32; msk >= 1; msk >>= 1) p += __shfl_xor(p, msk, 64);
                if (lane == 0)
                    scores[(size_t)(l0 + lo + li) * BB + b0 + rg * 4 + r] = p + blv;
            }
        }
        __syncthreads();
    }
}

// ---------------------------------------------------------------------------
// softmax over L + ctx from scores buffer. Block = 8 rows.
// ---------------------------------------------------------------------------
__global__ __launch_bounds__(256) void softmax_ctx(
    const float* __restrict__ scores, const float* __restrict__ enc_out,
    float* __restrict__ ctx)
{
    __shared__ float al_s[8 * 100];
    const int b0  = blockIdx.x * 8;
    const int tid = threadIdx.x;
    for (int v = tid; v < 800; v += 256) {
        int r = v / 100, l = v - r * 100;
        al_s[r * 100 + l] = scores[(size_t)l * BB + b0 + r];
    }
    __syncthreads();
    if (tid < 8) {
        float m = -1e30f;
        for (int l = 0; l < LL; ++l) m = fmaxf(m, al_s[tid * 100 + l]);
        float s = 0.f;
        for (int l = 0; l < LL; ++l) { float e = expf(al_s[tid * 100 + l] - m); al_s[tid * 100 + l] = e; s += e; }
        float inv = 1.f / s;
        for (int l = 0; l < LL; ++l) al_s[tid * 100 + l] *= inv;
    }
    __syncthreads();
    float acc[8] = {};
    for (int l = 0; l < LL; ++l) {
        const float* er = enc_out + (size_t)l * (BB * 256) + (size_t)b0 * 256 + tid;
        #pragma unroll
        for (int r = 0; r < 8; ++r) acc[r] += al_s[r * 100 + l] * er[r * 256];
    }
    for (int r = 0; r < 8; ++r) ctx[(size_t)(b0 + r) * 256 + tid] = acc[r];
}

// ---------------------------------------------------------------------------
// Decoder LSTM cell: grid 256 x 512, block = 8 rows, half0 = ctx@Wdi,
// half1 = hd@Wdh, coalesced float4 weights. hd updated in place.
// ---------------------------------------------------------------------------
__global__ __launch_bounds__(512) void dec_step(
    const float* __restrict__ ctxp,
    const float* __restrict__ Wdi, const float* __restrict__ Wdh,
    const float* __restrict__ bdec,
    float* __restrict__ hd, float* __restrict__ c_st, int first)
{
    __shared__ float ct_s[8 * 256];        // 8 KB
    __shared__ float hd_s[8 * 256];        // 8 KB
    __shared__ float gate_s[2][8 * 1024];  // 64 KB
    const int row0 = blockIdx.x * 8;
    const int tid  = threadIdx.x;
    const int lane = tid & 63, w = tid >> 6;
    const int half = tid >> 8;
    const int ct   = tid & 255;
    const int c0   = ct * 4;

    ((float4*)ct_s)[tid] = ((const float4*)(ctxp + (size_t)row0 * 256))[tid];
    if (!first)
        ((float4*)hd_s)[tid] = ((const float4*)(hd + (size_t)row0 * 256))[tid];
    __syncthreads();

    float4 acc[8];
    {
        float4 b4 = *(const float4*)&bdec[c0];
        float4 bias4 = (half == 0) ? b4 : make_float4(0.f, 0.f, 0.f, 0.f);
        #pragma unroll
        for (int r = 0; r < 8; ++r) acc[r] = bias4;
    }
    if (half == 0) {
        const float* wP = Wdi + c0;
        #pragma unroll 2
        for (int ch = 0; ch < 64; ++ch) {
            const int k0 = ch * 4;
            float4 w0 = *(const float4*)&wP[(size_t)(k0 + 0) * 1024];
            float4 w1 = *(const float4*)&wP[(size_t)(k0 + 1) * 1024];
            float4 w2 = *(const float4*)&wP[(size_t)(k0 + 2) * 1024];
            float4 w3 = *(const float4*)&wP[(size_t)(k0 + 3) * 1024];
            #pragma unroll
            for (int r = 0; r < 8; ++r) {
                float4 av = *(const float4*)&ct_s[r * 256 + k0];
                acc[r].x += av.x * w0.x; acc[r].y += av.x * w0.y;
                acc[r].z += av.x * w0.z; acc[r].w += av.x * w0.w;
                acc[r].x += av.y * w1.x; acc[r].y += av.y * w1.y;
                acc[r].z += av.y * w1.z; acc[r].w += av.y * w1.w;
                acc[r].x += av.z * w2.x; acc[r].y += av.z * w2.y;
                acc[r].z += av.z * w2.z; acc[r].w += av.z * w2.w;
                acc[r].x += av.w * w3.x; acc[r].y += av.w * w3.y;
                acc[r].z += av.w * w3.z; acc[r].w += av.w * w3.w;
            }
        }
    } else if (!first) {
        const float* wP = Wdh + c0;
        #pragma unroll 2
        for (int ch = 0; ch < 64; ++ch) {
            const int k0 = ch * 4;
            float4 w0 = *(const float4*)&wP[(size_t)(k0 + 0) * 1024];
            float4 w1 = *(const float4*)&wP[(size_t)(k0 + 1) * 1024];
            float4 w2 = *(const float4*)&wP[(size_t)(k0 + 2) * 1024];
            float4 w3 = *(const float4*)&wP[(size_t)(k0 + 3) * 1024];
            #pragma unroll
            for (int r = 0; r < 8; ++r) {
                float4 av = *(const float4*)&hd_s[r * 256 + k0];
                acc[r].x += av.x * w0.x; acc[r].y += av.x * w0.y;
                acc[r].z += av.x * w0.z; acc[r].w += av.x * w0.w;
                acc[r].x += av.y * w1.x; acc[r].y += av.y * w1.y;
                acc[r].z += av.y * w1.z; acc[r].w += av.y * w1.w;
                acc[r].x += av.z * w2.x; acc[r].y += av.z * w2.y;
                acc[r].z += av.z * w2.z; acc[r].w += av.z * w2.w;
                acc[r].x += av.w * w3.x; acc[r].y += av.w * w3.y;
                acc[r].z += av.w * w3.z; acc[r].w += av.w * w3.w;
            }
        }
    }
    #pragma unroll
    for (int r = 0; r < 8; ++r)
        *(float4*)&gate_s[half][r * 1024 + c0] = acc[r];
    __syncthreads();

    // epilogue: wave-local row w, lane -> 4 units
    {
        const float* g0 = &gate_s[0][w * 1024 + lane * 4];
        const float* g1 = &gate_s[1][w * 1024 + lane * 4];
        float4 giA = *(const float4*)&g0[0],   giB = *(const float4*)&g1[0];
        float4 gfA = *(const float4*)&g0[256], gfB = *(const float4*)&g1[256];
        float4 ggA = *(const float4*)&g0[512], ggB = *(const float4*)&g1[512];
        float4 goA = *(const float4*)&g0[768], goB = *(const float4*)&g1[768];
        size_t ci = (size_t)(row0 + w) * 256 + lane * 4;
        float4 c4 = first ? make_float4(0.f, 0.f, 0.f, 0.f)
                          : *(const float4*)&c_st[ci];
        float cc[4] = { c4.x, c4.y, c4.z, c4.w };
        float gi[4] = { giA.x + giB.x, giA.y + giB.y, giA.z + giB.z, giA.w + giB.w };
        float gf[4] = { gfA.x + gfB.x, gfA.y + gfB.y, gfA.z + gfB.z, gfA.w + gfB.w };
        float gg[4] = { ggA.x + ggB.x, ggA.y + ggB.y, ggA.z + ggB.z, ggA.w + ggB.w };
        float go[4] = { goA.x + goB.x, goA.y + goB.y, goA.z + goB.z, goA.w + goB.w };
        float4 cn, hn;
        #pragma unroll
        for (int uu = 0; uu < 4; ++uu) {
            float cv = sigmoidf_(gf[uu]) * cc[uu] + sigmoidf_(gi[uu]) * tanhf_(gg[uu]);
            float hv = sigmoidf_(go[uu]) * tanhf_(cv);
            if (uu == 0) { cn.x = cv; hn.x = hv; } else if (uu == 1) { cn.y = cv; hn.y = hv; }
            else if (uu == 2) { cn.z = cv; hn.z = hv; } else { cn.w = cv; hn.w = hv; }
        }
        *(float4*)&c_st[ci] = cn;
        *(float4*)&hd[ci]   = hn;
    }
}

// ---------------------------------------------------------------------------
// Head: fc = tanh(h_d@Wf+bf); out[:,step] = tanh(fc@Wo+bo). Block = 16 rows.
// ---------------------------------------------------------------------------
__global__ __launch_bounds__(256) void head_k(
    const float* __restrict__ hd, const float* __restrict__ Wf,
    const float* __restrict__ bf, const float* __restrict__ Wo,
    const float* __restrict__ bo, float* __restrict__ out, int step)
{
    __shared__ float hd_s[16 * 256];
    __shared__ float fc_s[16 * 128];
    const int b0  = blockIdx.x * 16;
    const int tid = threadIdx.x;
    {
        const float4* hg = (const float4*)(hd + (size_t)b0 * 256);
        for (int i = tid; i < 1024; i += 256) ((float4*)hd_s)[i] = hg[i];
    }
    __syncthreads();
    {
        const int f = tid & 127, rg = tid >> 7;
        float acc[8];
        float bfv = bf[f];
        #pragma unroll
        for (int rr = 0; rr < 8; ++rr) acc[rr] = bfv;
        const float* wp = Wf + f;
        #pragma unroll 2
        for (int k = 0; k < 256; ++k) {
            float wv = wp[k * 128];
            #pragma unroll
            for (int rr = 0; rr < 8; ++rr) acc[rr] += hd_s[(rg * 8 + rr) * 256 + k] * wv;
        }
        for (int rr = 0; rr < 8; ++rr) fc_s[(rg * 8 + rr) * 128 + f] = tanhf_(acc[rr]);
    }
    __syncthreads();
    {
        const int lane = tid & 63, w = tid >> 6;
        const float bov = bo[0];
        #pragma unroll
        for (int rr = 0; rr < 4; ++rr) {
            int r = w * 4 + rr;
            float p = fc_s[r * 128 + lane] * Wo[lane] + fc_s[r * 128 + 64 + lane] * Wo[64 + lane];
            #pragma unroll
            for (int msk = 32; msk >= 1; msk >>= 1) p += __shfl_xor(p, msk, 64);
            if (lane == 0) out[(size_t)(b0 + r) * NOUT + step] = tanhf_(p + bov);
        }
    }
}

extern "C" void kernel_launch(void* const* d_in, const int* in_sizes, int n_in,
                              void* d_out, int out_size, void* d_ws, size_t ws_size,
                              hipStream_t stream)
{
    const float* x    = (const float*)d_in[0];
    const float* Wa   = (const float*)d_in[1];
    const float* ba   = (const float*)d_in[2];
    const float* Wi   = (const float*)d_in[3];
    const float* Wh   = (const float*)d_in[4];
    const float* be   = (const float*)d_in[5];
    const float* Wd   = (const float*)d_in[6];
    const float* bd   = (const float*)d_in[7];
    const float* Wl   = (const float*)d_in[8];
    const float* bl   = (const float*)d_in[9];
    const float* Wdi  = (const float*)d_in[10];
    const float* Wdh  = (const float*)d_in[11];
    const float* bdec = (const float*)d_in[12];
    const float* Wf   = (const float*)d_in[13];
    const float* bf   = (const float*)d_in[14];
    const float* Wo   = (const float*)d_in[15];
    const float* bo   = (const float*)d_in[16];
    float* out = (float*)d_out;

    // ws layout (floats): enc_out | hd | c_d | ctx | scores  (~216.8 MB)
    const size_t f_enc    = (size_t)LL * BB * EE;     // 52,428,800
    const size_t f_state  = (size_t)BB * EE;          // 524,288
    const size_t f_scores = (size_t)LL * BB;          // 204,800
    const size_t need_f   = f_enc + 3 * f_state + f_scores;

    float* ws      = (float*)d_ws;
    float* enc_out = ws;
    float* hd      = enc_out + f_enc;
    float* c_d     = hd + f_state;
    float* ctx     = c_d + f_state;
    float* scores  = ctx + f_state;

    if (ws_size < need_f * sizeof(float)) return;   // diagnostic clean-fail

    // persistent encoder: one dispatch, 1024-thread blocks (4 waves/SIMD)
    enc_all<<<BB / 8, 1024, 0, stream>>>(x, Wa, ba, Wi, Wh, be, enc_out);

    for (int s = 0; s < NOUT; ++s) {
        scores_fused<<<dim3(BB / 16, 5), 256, 0, stream>>>(
            enc_out, Wd, bd, Wl, bl, hd, scores, s == 0);
        softmax_ctx<<<BB / 8, 256, 0, stream>>>(scores, enc_out, ctx);
        dec_step<<<BB / 8, 512, 0, stream>>>(ctx, Wdi, Wdh, bdec, hd, c_d, s == 0);
        head_k<<<BB / 16, 256, 0, stream>>>(hd, Wf, bf, Wo, bo, out, s);
    }
}